// Round 7
// baseline (841.210 us; speedup 1.0000x reference)
//
#include <hip/hip_runtime.h>
#include <cstdint>
#include <cstddef>

#define Hn 8192
#define Nn 4096
#define Cn 128
#define Tt 256
#define CAP 64

typedef unsigned long long ull;

// th after nup clip-updates (decay -0.05 each) from base b, clamped [lo,hi]
__device__ __forceinline__ float th_lazy2(float b, float lo, float hi, int nup){
    if (nup <= 0) return b;
    float a = fminf(fmaxf(__fsub_rn(b, 0.05f), lo), hi);
    if (nup == 1) return a;
    return fmaxf(__fsub_rn(a, __fmul_rn(0.05f, (float)(nup - 1))), lo);
}

__device__ __forceinline__ float clamp01(float v){
    return fminf(fmaxf(v, 0.f), 1.f);
}

// ---- DPP cross-lane reduce helpers (VALU pipe, no LDS) ----
template<int CTRL>
__device__ __forceinline__ int dpp_i(int x, int old){
    return __builtin_amdgcn_update_dpp(old, x, CTRL, 0xf, 0xf, false);
}

// max over 64 lanes of float, result uniform
__device__ __forceinline__ float wave_max_f(float v){
    const int NEG = __float_as_int(-3.4e38f);
#define STEPM(C) { float o = __int_as_float(dpp_i<C>(__float_as_int(v), NEG)); v = fmaxf(v, o); }
    STEPM(0x111) STEPM(0x112) STEPM(0x114) STEPM(0x118) STEPM(0x142) STEPM(0x143)
#undef STEPM
    return __int_as_float(__builtin_amdgcn_readlane(__float_as_int(v), 63));
}

// min over 64 lanes of unsigned key with carried int payload; results uniform
__device__ __forceinline__ void wave_min_key_pay(unsigned &k, int &p){
#define STEPN(C) { unsigned k2 = (unsigned)dpp_i<C>((int)k, (int)0xFFFFFFFFu); \
                   int p2 = dpp_i<C>(p, 0); \
                   if (k2 < k){ k = k2; p = p2; } }
    STEPN(0x111) STEPN(0x112) STEPN(0x114) STEPN(0x118) STEPN(0x142) STEPN(0x143)
#undef STEPN
    k = (unsigned)__builtin_amdgcn_readlane((int)k, 63);
    p = __builtin_amdgcn_readlane(p, 63);
}

// ---------------- k_prep: start buckets + deterministic counting sort (1024 thr) ----------------
__global__ __launch_bounds__(1024) void k_prep(const float* __restrict__ image,
        int* __restrict__ boff, int* __restrict__ sidx, unsigned* __restrict__ anyv){
    __shared__ int s_start[Nn];
    __shared__ int s_c4[4][Tt];
    __shared__ int s_boff[Tt + 1];
    int tid = threadIdx.x;
    for (int i = tid; i < Nn; i += 1024)
        s_start[i] = (int)floorf(__fmul_rn(256.f, image[i]));
    if (tid < Tt) anyv[tid] = 0u;
    __syncthreads();
    int b = tid & 255, q = tid >> 8;
    {
        int c = 0;
        for (int k = 0; k < 1024; ++k) c += (s_start[q * 1024 + k] == b) ? 1 : 0;
        s_c4[q][b] = c;
    }
    __syncthreads();
    if (tid == 0){
        int acc = 0;
        for (int bb = 0; bb < Tt; ++bb){
            s_boff[bb] = acc;
            acc += s_c4[0][bb] + s_c4[1][bb] + s_c4[2][bb] + s_c4[3][bb];
        }
        s_boff[Tt] = acc;
    }
    __syncthreads();
    if (tid <= Tt) boff[tid] = s_boff[tid];
    int p = s_boff[b];
    if (q > 0) p += s_c4[0][b];
    if (q > 1) p += s_c4[1][b];
    if (q > 2) p += s_c4[2][b];
    for (int k = 0; k < 1024; ++k){
        int i = q * 1024 + k;
        if (s_start[i] == b) sidx[p++] = i;
    }
}

// ---------------- k_gbuckets: G_T[h][t] = sum_{i in bucket t} W1[h][i] ----------------
__global__ __launch_bounds__(256) void k_gbuckets(const float* __restrict__ W1,
        const int* __restrict__ boff, const int* __restrict__ sidx,
        float* __restrict__ G_T){
    __shared__ float rows[4][Nn]; // 64 KB
    int tid = threadIdx.x;
    int h0 = blockIdx.x * 4;
    for (int r = 0; r < 4; ++r){
        const float4* src = (const float4*)(W1 + (size_t)(h0 + r) * Nn);
        float4* dst = (float4*)rows[r];
        for (int j = tid; j < Nn / 4; j += 256) dst[j] = src[j];
    }
    __syncthreads();
    int t = tid;
    int b0 = boff[t], b1 = boff[t + 1];
    float s0 = 0.f, s1 = 0.f, s2 = 0.f, s3 = 0.f;
    for (int k = b0; k < b1; ++k){
        int i = sidx[k];
        s0 += rows[0][i]; s1 += rows[1][i]; s2 += rows[2][i]; s3 += rows[3][i];
    }
    G_T[(size_t)(h0 + 0) * Tt + t] = s0;
    G_T[(size_t)(h0 + 1) * Tt + t] = s1;
    G_T[(size_t)(h0 + 2) * Tt + t] = s2;
    G_T[(size_t)(h0 + 3) * Tt + t] = s3;
}

// ---------------- k_c1M: fused window-sum + M-scan + c1T transpose + r1 init ----------------
__global__ __launch_bounds__(256) void k_c1M(const float* __restrict__ G_T,
        float* __restrict__ c1T, float* __restrict__ M,
        float* __restrict__ r1pre, float* __restrict__ o_r1){
    __shared__ float tile[32][Tt + 1];
    __shared__ float c1s[32][Tt + 1];
    const int tid = threadIdx.x;
    const int h0 = blockIdx.x * 32;
    for (int r = 0; r < 32; ++r) tile[r][tid] = G_T[(size_t)(h0 + r) * Tt + tid];
    __syncthreads();
    {
        int hs = tid & 31, ts = tid >> 5;
        for (int tb = 0; tb < 32; ++tb){
            int t = tb * 8 + ts;
            int lo = (t - 7 < 0) ? 0 : t - 7;
            float s = 0.f;
            for (int u = lo; u <= t; ++u) s += tile[hs][u];
            c1s[hs][t] = s;
        }
    }
    __syncthreads();
    if (tid < 32){
        float m = 0.f;
        for (int t = 0; t < Tt; ++t){
            m = __fadd_rn(__fmul_rn(0.9f, m), c1s[tid][t]);
            M[(size_t)t * Hn + h0 + tid] = m;
        }
        r1pre[h0 + tid] = 0.f;
        o_r1[h0 + tid] = 256.f;
    }
    {
        int hr = tid >> 3, qq = tid & 7;
        float* drow = c1T + (size_t)(h0 + hr) * Tt + qq * 32;
        for (int k = 0; k < 8; ++k){
            float4 v = make_float4(c1s[hr][qq*32 + 4*k], c1s[hr][qq*32 + 4*k + 1],
                                   c1s[hr][qq*32 + 4*k + 2], c1s[hr][qq*32 + 4*k + 3]);
            ((float4*)drow)[k] = v;
        }
    }
}

// ---------------- k_sel: exact rank-CAP radix-select; emits val/meta/vcap ----------------
// meta: bits[12:0]=idx, bit13=fire_if_winner (val > th_eff), bit15=valid
__global__ __launch_bounds__(256) void k_sel(const float* __restrict__ M,
        const float* __restrict__ thr1, float* __restrict__ gval,
        unsigned short* __restrict__ gmeta, float* __restrict__ gvcap){
    const int t = blockIdx.x, tid = threadIdx.x;
    __shared__ float s_row[Hn];        // 32 KB
    __shared__ unsigned s_hist[256];
    __shared__ unsigned s_suf[256];
    __shared__ unsigned s_pref;
    __shared__ int s_rank;
    __shared__ int s_cnt;
    __shared__ int s_idx[CAP + 64];
    {
        const float4* src = (const float4*)(M + (size_t)t * Hn);
        float4* d4 = (float4*)s_row;
        for (int j = tid; j < Hn / 4; j += 256) d4[j] = src[j];
    }
    if (tid == 0){ s_pref = 0u; s_rank = CAP; s_cnt = 0; }
    __syncthreads();
#pragma unroll
    for (int b = 3; b >= 0; --b){
        s_hist[tid] = 0u;
        __syncthreads();
        unsigned pref = s_pref;
        int r = s_rank;
        for (int k = 0; k < 32; ++k){
            unsigned u = __float_as_uint(s_row[tid + (k << 8)]);
            bool match = (b == 3) ? true : ((u >> ((b + 1) * 8)) == pref);
            if (match) atomicAdd(&s_hist[(u >> (b * 8)) & 255], 1u);
        }
        __syncthreads();
        s_suf[tid] = s_hist[tid];
        __syncthreads();
#pragma unroll
        for (int off = 1; off < 256; off <<= 1){
            unsigned v = (tid + off < 256) ? s_suf[tid + off] : 0u;
            __syncthreads();
            s_suf[tid] += v;
            __syncthreads();
        }
        unsigned above = s_suf[tid] - s_hist[tid];
        if ((int)above < r && r <= (int)s_suf[tid]){
            s_pref = (pref << 8) | (unsigned)tid;
            s_rank = r - (int)above;
        }
        __syncthreads();
    }
    unsigned V = s_pref;
    for (int k = 0; k < 32; ++k){
        int i = tid + (k << 8);
        unsigned u = __float_as_uint(s_row[i]);
        if (u >= V){
            int p = atomicAdd(&s_cnt, 1);
            if (p < CAP + 64) s_idx[p] = i;
        }
    }
    __syncthreads();
    int c = s_cnt;
    bool ovf = (c > CAP);
    if (tid == 0) gvcap[t] = ovf ? 3.4e38f : __uint_as_float(V);
    for (int i = tid; i < CAP; i += 256){
        float v; unsigned short m;
        if (!ovf && i < c){
            int ix = s_idx[i];
            v = s_row[ix];
            float te = th_lazy2(thr1[ix], 150.f, 400.f, t);
            m = (unsigned short)((unsigned)ix | ((v > te) ? 0x2000u : 0u) | 0x8000u);
        } else {
            v = -1.f; m = 0;
        }
        gval[(size_t)t * CAP + i] = v;
        gmeta[(size_t)t * CAP + i] = m;
    }
}

// ---------------- k_wta1: single-wave serial WTA; everything hot in LDS ----------------
__global__ __launch_bounds__(64, 1) void k_wta1(
        const float* __restrict__ M, const float* __restrict__ c1T,
        const float* __restrict__ gval, const unsigned short* __restrict__ gmeta,
        const float* __restrict__ gvcap, const float* __restrict__ thr1,
        float* __restrict__ r1pre, float* __restrict__ o_r1,
        int* __restrict__ j1s, int* __restrict__ mh, int* __restrict__ nRout){
    const int lane = threadIdx.x;
    __shared__ __align__(16) float s_val[Tt * CAP];            // 64 KB
    __shared__ __align__(16) unsigned short s_meta[Tt * CAP];  // 32 KB
    __shared__ __align__(16) float s_thr1[Hn];                 // 32 KB
    __shared__ __align__(16) float s_vcap[Tt];                 // 1 KB
    __shared__ unsigned s_bitw[Hn / 32];                       // 1 KB
    __shared__ int s_j1[Tt];                                   // 1 KB
    __shared__ int s_mh[Tt];                                   // 1 KB

    // bulk global -> LDS staging
    {
        const float4* s = (const float4*)gval; float4* d = (float4*)s_val;
        for (int i = lane; i < Tt * CAP / 4; i += 64) d[i] = s[i];
    }
    {
        const uint4* s = (const uint4*)gmeta; uint4* d = (uint4*)s_meta;
        for (int i = lane; i < Tt * CAP * 2 / 16; i += 64) d[i] = s[i];
    }
    {
        const float4* s = (const float4*)thr1; float4* d = (float4*)s_thr1;
        for (int i = lane; i < Hn / 4; i += 64) d[i] = s[i];
    }
    {
        const float4* s = (const float4*)gvcap; float4* d = (float4*)s_vcap;
        for (int i = lane; i < Tt / 4; i += 64) d[i] = s[i];
    }
    for (int i = lane; i < Hn / 32; i += 64) s_bitw[i] = 0u;
    __syncthreads();

    int   sh0=-1,sh1=-1,sh2=-1,sh3=-1;
    float sm0=0.f,sm1=0.f,sm2=0.f,sm3=0.f;
    float st0=0.f,st1=0.f,st2=0.f,st3=0.f;
    int   ss0=0,ss1=0,ss2=0,ss3=0;
    float sr0=0.f,sr1=0.f,sr2=0.f,sr3=0.f;
    float4 z4 = make_float4(0.f,0.f,0.f,0.f);
    float4 dA0=z4,dA1=z4,dA2=z4,dA3=z4,dB0=z4,dB1=z4,dB2=z4,dB3=z4;
    int nR = 0;

    // candidate prefetch: A = step t, B = step t+1
    float    cvA = s_val[lane];
    unsigned cmA = (unsigned)s_meta[lane];
    float    cvB = s_val[CAP + lane];
    unsigned cmB = (unsigned)s_meta[CAP + lane];
    int mbA = 0;                       // membership of A's candidate (bitmap empty at t=0)
    float vcA = s_vcap[0], vcB = s_vcap[1];

    for (int t = 0; t < Tt; ++t){
        const int g = t >> 2, jj = t & 3;
        // [1] member update + local best (pay=0 marks member origin)
        float bv = -3.4e38f; int bh = 0x7FFFFFFF; int pay = 0;
#define UPD(i) if (sh##i >= 0){ \
            float dv = (jj==0)?dA##i.x:(jj==1)?dA##i.y:(jj==2)?dA##i.z:dA##i.w; \
            sm##i = __fadd_rn(__fmul_rn(0.9f, sm##i), dv); \
            if (sm##i > bv || (sm##i == bv && sh##i < bh)){ bv = sm##i; bh = sh##i; } }
        UPD(0) UPD(1) UPD(2) UPD(3)
#undef UPD
        // [2] candidate merge (1 per lane)
        const int ciA = (int)(cmA & 8191u);
        const int vnm = (int)((cmA >> 15) & 1u) & (mbA ^ 1);
        if (vnm && (cvA > bv || (cvA == bv && ciA < bh))){
            bv = cvA; bh = ciA; pay = 2 | (int)((cmA >> 13) & 1u);
        }
        ull anyNM = __ballot(vnm != 0);
        // [3] DPP argmax (value desc, index asc) carrying pay
        float wv = wave_max_f(bv);
        unsigned key = (bv == wv) ? (unsigned)bh : 0xFFFFFFFFu;
        int py = pay;
        wave_min_key_pay(key, py);
        int wh = (int)key;
        // [4] guards
        int didFB = 0, skip = 0;
        if (anyNM == 0ull){
            if (wv >= vcA){
                // best evaluated dominates all unlisted non-members: exact
            } else if (t > 0 && vcA < 150.f){
                skip = 1;
            } else {
                // rare exact fallback: full-row scan over non-members (+ member slots)
                float fv = -3.4e38f; int fh = 0x7FFFFFFF;
#define RES(i) if (sh##i >= 0 && (sm##i > fv || (sm##i == fv && sh##i < fh))){ fv = sm##i; fh = sh##i; }
                RES(0) RES(1) RES(2) RES(3)
#undef RES
                const float4* Mrow4 = (const float4*)(M + (size_t)t * Hn);
                for (int q = 0; q < 32; ++q){
                    int e = q * 64 + lane;
                    float4 mv = Mrow4[e];
                    int ib = e * 4;
                    unsigned wb = s_bitw[ib >> 5];
                    if (!((wb >> ((ib+0) & 31)) & 1u) && (mv.x > fv || (mv.x == fv && ib+0 < fh))){ fv = mv.x; fh = ib+0; }
                    if (!((wb >> ((ib+1) & 31)) & 1u) && (mv.y > fv || (mv.y == fv && ib+1 < fh))){ fv = mv.y; fh = ib+1; }
                    if (!((wb >> ((ib+2) & 31)) & 1u) && (mv.z > fv || (mv.z == fv && ib+2 < fh))){ fv = mv.z; fh = ib+2; }
                    if (!((wb >> ((ib+3) & 31)) & 1u) && (mv.w > fv || (mv.w == fv && ib+3 < fh))){ fv = mv.w; fh = ib+3; }
                }
                wv = wave_max_f(fv);
                unsigned k2 = (fv == wv) ? (unsigned)fh : 0xFFFFFFFFu;
                int p2 = 0;
                wave_min_key_pay(k2, p2);
                wh = (int)k2;
                didFB = 1;
            }
        }
        // [5] decision
        if (!skip){
            int m0=(sh0==wh), m1=(sh1==wh), m2=(sh2==wh), m3=(sh3==wh);
            ull memMask = __ballot(m0 | m1 | m2 | m3);
            if (memMask != 0ull){
                int fflag = 0, jsl = -1;
#define DSL(i) if (m##i){ int nup = t - ss##i - 1; float te = th_lazy2(st##i, 150.f, 400.f, nup); \
                  if (wv > te){ fflag = 1; sm##i = 0.f; \
                      st##i = fminf(fmaxf(__fadd_rn(__fsub_rn(te,0.05f),5.0f),150.f),400.f); ss##i = t; \
                      jsl = (i << 6) | lane; } }
                DSL(0) DSL(1) DSL(2) DSL(3)
#undef DSL
                ull fm = __ballot(fflag);
                if (fm != 0ull){ if (fflag) s_j1[t] = jsl; }
                else if (lane == 0) s_j1[t] = -1;
            } else {
                float te_b = th_lazy2(s_thr1[wh], 150.f, 400.f, t);
                int fire = didFB ? ((wv > te_b) ? 1 : 0) : (py & 1);
                if (fire){
                    float thnew = fminf(fmaxf(__fadd_rn(__fsub_rn(te_b,0.05f),5.0f),150.f),400.f);
                    if (lane == (nR & 63)){
                        const float4* crow = (const float4*)(c1T + (size_t)wh * Tt);
                        int g1 = (g + 1 < 64) ? g + 1 : 63;
                        int srg = nR >> 6;
#define JN(i) { sh##i = wh; sm##i = 0.f; st##i = thnew; ss##i = t; sr##i = (float)(t+1); \
                dA##i = crow[g]; dB##i = crow[g1]; }
                        if (srg == 0){ JN(0) } else if (srg == 1){ JN(1) }
                        else if (srg == 2){ JN(2) } else { JN(3) }
#undef JN
                        s_j1[t] = nR;
                        s_mh[nR] = wh;
                    }
                    if (lane == 0) atomicOr(&s_bitw[wh >> 5], 1u << (wh & 31));
                    nR++;
                } else {
                    if (lane == 0) s_j1[t] = -1;
                }
            }
        } else {
            if (lane == 0) s_j1[t] = -1;
        }
        // [6] member-drive rotation every 4 steps
        if (jj == 3 && g < 63){
            int g2 = (g + 2 < 64) ? g + 2 : 63;
#define RT(i) { dA##i = dB##i; if (sh##i >= 0) dB##i = ((const float4*)(c1T + (size_t)sh##i * Tt))[g2]; }
            RT(0) RT(1) RT(2) RT(3)
#undef RT
        }
        // [7] next-step prefetch (membership read AFTER this step's join write)
        int mbN;
        {
            int cin = (int)(cmB & 8191u);
            unsigned wbits = s_bitw[cin >> 5];
            mbN = (int)((wbits >> (cin & 31)) & 1u);
        }
        int tn = (t + 2 < Tt) ? t + 2 : Tt - 1;
        float    cvN = s_val[tn * CAP + lane];
        unsigned cmN = (unsigned)s_meta[tn * CAP + lane];
        float    vcN = s_vcap[tn];
        cvA = cvB; cmA = cmB; mbA = mbN; vcA = vcB;
        cvB = cvN; cmB = cmN; vcB = vcN;
    }
#define WB(i) if (sh##i >= 0){ r1pre[sh##i] = sr##i; o_r1[sh##i] = sr##i; }
    WB(0) WB(1) WB(2) WB(3)
#undef WB
    for (int i = lane; i < Tt; i += 64){ j1s[i] = s_j1[i]; mh[i] = s_mh[i]; }
    if (lane == 0) *nRout = nR;
}

// ---------------- k_colg: gather distinct member columns of W2 ----------------
__global__ __launch_bounds__(256) void k_colg(const float* __restrict__ W2,
        const int* __restrict__ mh, const int* __restrict__ nRout,
        float* __restrict__ colv){
    int slot = blockIdx.x;
    if (slot >= *nRout) return;
    int h = mh[slot];
    int tid = threadIdx.x;
    float* dst = colv + (size_t)slot * Nn;
    for (int n = tid; n < Nn; n += 256) dst[n] = W2[(size_t)n * Hn + h];
}

// ---------------- k_lif2: layer 2 per-neuron LIF, ballot spike masks ----------------
__global__ __launch_bounds__(64) void k_lif2(const float* __restrict__ colv,
        const int* __restrict__ j1s, const float* __restrict__ thr2,
        float* __restrict__ o_r2, ull* __restrict__ spkb, unsigned* __restrict__ anyv){
    __shared__ int s_j[Tt];
    int lane = threadIdx.x, blk = blockIdx.x;
    for (int i = lane; i < Tt; i += 64) s_j[i] = j1s[i];
    __syncthreads();
    int n = blk * 64 + lane;
    float tv = thr2[n], m = 0.f, rp = 0.f;
    for (int t = 0; t < Tt; ++t){
        int s = s_j[t];
        float u = (s >= 0) ? colv[(size_t)s * Nn + n] : 0.f;
        m = __fadd_rn(__fmul_rn(0.8f, m), u);
        int f = 0;
        if (m > tv){
            m = __fsub_rn(m, tv);
            if (rp == 0.f) rp = (float)(t + 1);
            f = 1;
        }
        ull mask = __ballot(f);
        if (lane == 0){
            spkb[t * 64 + blk] = mask;
            if (mask) atomicOr(&anyv[t], 1u);
        }
    }
    o_r2[n] = (rp == 0.f) ? 256.f : rp;
}

// ---------------- k_w3t: W3T[n][c] = W3[c][n] ----------------
__global__ __launch_bounds__(256) void k_w3t(const float* __restrict__ W3,
                                             float* __restrict__ W3T){
    __shared__ float tl[64][65];
    int bx = blockIdx.x & 63, by = blockIdx.x >> 6;
    int n0 = bx * 64, c0 = by * 64;
    int tid = threadIdx.x;
    for (int e = tid; e < 64 * 64; e += 256){
        int r = e >> 6, cc = e & 63;
        tl[r][cc] = W3[(size_t)(c0 + r) * Nn + n0 + cc];
    }
    __syncthreads();
    for (int e = tid; e < 64 * 64; e += 256){
        int rn = e >> 6, cc = e & 63;
        W3T[(size_t)(n0 + rn) * Cn + c0 + cc] = tl[cc][rn];
    }
}

// ---------------- k_sim3: layer 3 WTA; skips exact-zero quiet steps ----------------
__global__ __launch_bounds__(128, 1) void k_sim3(const ull* __restrict__ spkb,
        const unsigned* __restrict__ anyv, const float* __restrict__ W3T,
        const float* __restrict__ thr3, float* __restrict__ o_r3){
    int tid = threadIdx.x, lane = tid & 63, w = tid >> 6;
    __shared__ unsigned s_any[Tt];
    __shared__ ull s_r2[2];
    __shared__ int s_fire;
    for (int i = tid; i < Tt; i += 128) s_any[i] = anyv[i];
    float m = 0.f, th0 = thr3[tid], rp = 0.f, thv = 0.f;
    int ts = -1, zero = 1;
    __syncthreads();
    for (int t = 0; t < Tt; ++t){
        if (zero && s_any[t] == 0u) continue;
        float d = 0.f;
        if (s_any[t]){
            for (int ww = 0; ww < 64; ++ww){
                ull bits = spkb[t * 64 + ww];
                while (bits){
                    int b2 = __ffsll((long long)bits) - 1;
                    bits &= bits - 1;
                    d = __fadd_rn(d, W3T[(size_t)(ww * 64 + b2) * Cn + tid]);
                }
            }
        }
        m = __fadd_rn(__fmul_rn(0.9f, m), d);
        ull k = (((ull)__float_as_uint(m >= 0.f ? m : 0.f)) << 32) | (unsigned)(8191 - tid);
        if (!(m >= 0.f)) k = (unsigned)(8191 - tid);
#pragma unroll
        for (int off = 32; off >= 1; off >>= 1){
            ull o = __shfl_down(k, off);
            if (o > k) k = o;
        }
        if (lane == 0) s_r2[w] = k;
        __syncthreads();
        ull wk = s_r2[0] > s_r2[1] ? s_r2[0] : s_r2[1];
        int wc = 8191 - (int)(wk & 0xFFFFu);
        float wv = __uint_as_float((unsigned)(wk >> 32));
        if (tid == wc){
            float te = (ts < 0) ? th_lazy2(th0, 50.f, 200.f, t)
                                : th_lazy2(thv, 50.f, 200.f, t - ts - 1);
            int f = (wv > te) ? 1 : 0;
            s_fire = f;
            if (f){
                thv = fminf(fmaxf(__fadd_rn(__fsub_rn(te, 0.05f), 5.0f), 50.f), 200.f);
                ts = t;
                if (rp == 0.f) rp = (float)(t + 1);
            }
        }
        __syncthreads();
        if (s_fire){ m = 0.f; zero = 1; }
        else zero = 0;
        __syncthreads();
    }
    o_r3[tid] = (rp == 0.f) ? 256.f : rp;
}

// ---------------- k_scalars: zeta/rho/error + factored exp tables ----------------
__global__ __launch_bounds__(1024) void k_scalars(const float* __restrict__ image,
        const float* __restrict__ r1pre, const float* __restrict__ o_r1,
        const float* __restrict__ o_r2,
        float* __restrict__ zeta, float* __restrict__ rho,
        float* __restrict__ imgt, float* __restrict__ eiP, float* __restrict__ eiM,
        float* __restrict__ Pv, float* __restrict__ Qv,
        float* __restrict__ E2P, float* __restrict__ E2M,
        float* __restrict__ o_err, float* __restrict__ o_es){
    int tid = threadIdx.x;
    for (int h = tid; h < Hn; h += 1024){
        float r1f = o_r1[h];
        float mask = (r1pre[h] != 0.f) ? 1.f : 0.f;
        float z = __fmul_rn(__fmul_rn(__fsub_rn(256.f, r1f), mask), 0.00390625f);
        zeta[h] = z;
        Pv[h] = __expf(r1f * 0.05f) * z;
        Qv[h] = __expf(-r1f * 0.05f) * z;
    }
    float acc = 0.f;
    for (int n = tid; n < Nn; n += 1024){
        float img = __fmul_rn(256.f, image[n]);
        float r2f = o_r2[n];
        float e = __fmul_rn(__fsub_rn(img, __fsub_rn(r2f, 4.0f)), 0.00390625f);
        o_err[n] = e;
        rho[n] = __fadd_rn(__fmul_rn(__fsub_rn(__fsub_rn(r2f, 4.0f), img), 0.00390625f), 0.15f);
        imgt[n] = img;
        eiP[n] = __expf(img * 0.05f);
        eiM[n] = __expf(-img * 0.05f);
        E2P[n] = __expf(r2f * 0.05f);
        E2M[n] = __expf(-r2f * 0.05f);
        acc = __fadd_rn(acc, __fmul_rn(e, e));
    }
    __shared__ float red[16];
    for (int off = 32; off >= 1; off >>= 1) acc += __shfl_down(acc, off);
    int lane = tid & 63, w = tid >> 6;
    if (lane == 0) red[w] = acc;
    __syncthreads();
    if (tid == 0){
        float s = 0.f;
        for (int q = 0; q < 16; ++q) s += red[q];
        *o_es = s;
    }
}

// ---------------- STDP weight updates (factored exp, float4 streams) ----------------
__global__ __launch_bounds__(256) void k_w1new(const float* __restrict__ W1,
        const float* __restrict__ imgt, const float* __restrict__ eiP,
        const float* __restrict__ eiM, const float* __restrict__ r1pre,
        const float* __restrict__ o_r1, float* __restrict__ o_W1){
    int h = blockIdx.x, tid = threadIdx.x;
    float r1f = o_r1[h];
    bool msk = (r1pre[h] != 0.f);
    float a = 0.01f * __expf(-r1f * 0.05f);
    float b = 0.01f * __expf( r1f * 0.05f);
    const float4* src = (const float4*)(W1 + (size_t)h * Nn);
    float4* dst = (float4*)(o_W1 + (size_t)h * Nn);
    const float4* ig = (const float4*)imgt;
    const float4* p4 = (const float4*)eiP;
    const float4* m4 = (const float4*)eiM;
    for (int i = tid; i < Nn / 4; i += 256){
        float4 s = src[i];
        if (msk){
            float4 im = ig[i], pp = p4[i], mm = m4[i];
            s.x += (r1f >= im.x) ? a * pp.x : -(b * mm.x);
            s.y += (r1f >= im.y) ? a * pp.y : -(b * mm.y);
            s.z += (r1f >= im.z) ? a * pp.z : -(b * mm.z);
            s.w += (r1f >= im.w) ? a * pp.w : -(b * mm.w);
        } else {
            s.x += 0.01f; s.y += 0.01f; s.z += 0.01f; s.w += 0.01f;
        }
        dst[i] = s;
    }
}

__global__ __launch_bounds__(256) void k_w2new(const float* __restrict__ W2,
        const float* __restrict__ o_r1, const float* __restrict__ Pv,
        const float* __restrict__ Qv, const float* __restrict__ o_r2,
        const float* __restrict__ rho, float* __restrict__ o_W2){
    int n = blockIdx.x, tid = threadIdx.x;
    float r2f = o_r2[n], rh = rho[n];
    float A = 0.01f * rh * __expf(-r2f * 0.05f);
    float B = 0.01f * rh * __expf( r2f * 0.05f);
    const float4* src = (const float4*)(W2 + (size_t)n * Hn);
    float4* dst = (float4*)(o_W2 + (size_t)n * Hn);
    const float4* r14 = (const float4*)o_r1;
    const float4* p4 = (const float4*)Pv;
    const float4* q4 = (const float4*)Qv;
    for (int i = tid; i < Hn / 4; i += 256){
        float4 s = src[i]; float4 rv = r14[i]; float4 pp = p4[i]; float4 qq = q4[i];
        s.x = clamp01(s.x + ((r2f >= rv.x) ? A * pp.x : -(B * qq.x)));
        s.y = clamp01(s.y + ((r2f >= rv.y) ? A * pp.y : -(B * qq.y)));
        s.z = clamp01(s.z + ((r2f >= rv.z) ? A * pp.z : -(B * qq.z)));
        s.w = clamp01(s.w + ((r2f >= rv.w) ? A * pp.w : -(B * qq.w)));
        dst[i] = s;
    }
}

__global__ __launch_bounds__(256) void k_w3new(const float* __restrict__ W3,
        const float* __restrict__ o_r2, const float* __restrict__ E2P,
        const float* __restrict__ E2M, const float* __restrict__ o_r3,
        float* __restrict__ o_W3){
    int c = blockIdx.x, tid = threadIdx.x;
    float r3f = o_r3[c];
    float a = 0.01f * __expf(-r3f * 0.05f);
    float b = 0.01f * __expf( r3f * 0.05f);
    const float4* src = (const float4*)(W3 + (size_t)c * Nn);
    float4* dst = (float4*)(o_W3 + (size_t)c * Nn);
    const float4* r24 = (const float4*)o_r2;
    const float4* p4 = (const float4*)E2P;
    const float4* m4 = (const float4*)E2M;
    for (int i = tid; i < Nn / 4; i += 256){
        float4 s = src[i]; float4 rv = r24[i]; float4 pp = p4[i]; float4 mm = m4[i];
        s.x += (r3f >= rv.x) ? a * pp.x : -(b * mm.x);
        s.y += (r3f >= rv.y) ? a * pp.y : -(b * mm.y);
        s.z += (r3f >= rv.z) ? a * pp.z : -(b * mm.z);
        s.w += (r3f >= rv.w) ? a * pp.w : -(b * mm.w);
        dst[i] = s;
    }
}

extern "C" void kernel_launch(void* const* d_in, const int* in_sizes, int n_in,
                              void* d_out, int out_size, void* d_ws, size_t ws_size,
                              hipStream_t stream){
    const float* image = (const float*)d_in[0];
    const float* W1   = (const float*)d_in[1];
    const float* W2   = (const float*)d_in[2];
    const float* W3   = (const float*)d_in[3];
    const float* thr1 = (const float*)d_in[4];
    const float* thr2 = (const float*)d_in[5];
    const float* thr3 = (const float*)d_in[6];

    float* out  = (float*)d_out;
    float* o_err = out;                       // [4096]
    float* o_es  = out + 4096;                // [1]
    float* o_r1  = out + 4097;                // [8192]
    float* o_r2  = out + 12289;               // [4096]
    float* o_r3  = out + 16385;               // [128]
    float* o_W1  = out + 16513;               // [8192*4096]
    float* o_W2  = o_W1 + (size_t)Hn * Nn;    // [4096*8192]
    float* o_W3  = o_W2 + (size_t)Nn * Hn;    // [128*4096]

    float* ws = (float*)d_ws;
    float* G_T   = ws;                                  // H*T
    float* c1T   = G_T + (size_t)Hn * Tt;               // H*T
    float* M     = c1T + (size_t)Hn * Tt;               // T*H
    float* W3T   = M + (size_t)Tt * Hn;                 // N*C
    float* colv  = W3T + (size_t)Nn * Cn;               // 256*N
    float* gval  = colv + (size_t)256 * Nn;             // T*CAP
    float* gvcap = gval + (size_t)Tt * CAP;             // T
    unsigned short* gmeta = (unsigned short*)(gvcap + Tt);        // T*CAP u16
    ull* spkb    = (ull*)(((char*)gmeta) + (size_t)Tt * CAP * 2); // T*64 u64
    float* r1pre = (float*)(spkb + (size_t)Tt * 64);    // H
    float* zeta  = r1pre + Hn;                          // H
    float* rho   = zeta + Hn;                           // N
    float* imgt  = rho + Nn;                            // N
    float* eiP   = imgt + Nn;                           // N
    float* eiM   = eiP + Nn;                            // N
    float* Pv    = eiM + Nn;                            // H
    float* Qv    = Pv + Hn;                             // H
    float* E2P   = Qv + Hn;                             // N
    float* E2M   = E2P + Nn;                            // N
    int* boff  = (int*)(E2M + Nn);                      // T+1
    int* sidx  = boff + (Tt + 1);                       // N
    int* j1s   = sidx + Nn;                             // T
    int* mh    = j1s + Tt;                              // 256
    int* nRout = mh + 256;                              // 1
    unsigned* anyv = (unsigned*)(nRout + 1);            // T

    k_prep<<<1, 1024, 0, stream>>>(image, boff, sidx, anyv);
    k_gbuckets<<<Hn / 4, 256, 0, stream>>>(W1, boff, sidx, G_T);
    k_c1M<<<Hn / 32, 256, 0, stream>>>(G_T, c1T, M, r1pre, o_r1);
    k_sel<<<Tt, 256, 0, stream>>>(M, thr1, gval, gmeta, gvcap);
    k_wta1<<<1, 64, 0, stream>>>(M, c1T, gval, gmeta, gvcap, thr1, r1pre, o_r1, j1s, mh, nRout);
    k_colg<<<256, 256, 0, stream>>>(W2, mh, nRout, colv);
    k_lif2<<<Nn / 64, 64, 0, stream>>>(colv, j1s, thr2, o_r2, spkb, anyv);
    k_w3t<<<128, 256, 0, stream>>>(W3, W3T);
    k_sim3<<<1, 128, 0, stream>>>(spkb, anyv, W3T, thr3, o_r3);
    k_scalars<<<1, 1024, 0, stream>>>(image, r1pre, o_r1, o_r2, zeta, rho,
                                      imgt, eiP, eiM, Pv, Qv, E2P, E2M, o_err, o_es);
    k_w1new<<<Hn, 256, 0, stream>>>(W1, imgt, eiP, eiM, r1pre, o_r1, o_W1);
    k_w2new<<<Nn, 256, 0, stream>>>(W2, o_r1, Pv, Qv, o_r2, rho, o_W2);
    k_w3new<<<Cn, 256, 0, stream>>>(W3, o_r2, E2P, E2M, o_r3, o_W3);
}

// Round 8
// 808.255 us; speedup vs baseline: 1.0408x; 1.0408x over previous
//
#include <hip/hip_runtime.h>
#include <cstdint>
#include <cstddef>

#define Hn 8192
#define Nn 4096
#define Cn 128
#define Tt 256
#define CAP 192

typedef unsigned long long ull;

// th after nup clip-updates (decay -0.05 each) from base b, clamped [lo,hi]
__device__ __forceinline__ float th_lazy2(float b, float lo, float hi, int nup){
    if (nup <= 0) return b;
    float a = fminf(fmaxf(__fsub_rn(b, 0.05f), lo), hi);
    if (nup == 1) return a;
    return fmaxf(__fsub_rn(a, __fmul_rn(0.05f, (float)(nup - 1))), lo);
}

__device__ __forceinline__ float clamp01(float v){
    return fminf(fmaxf(v, 0.f), 1.f);
}

// ---- DPP cross-lane reduce (VALU pipe) ----
template<int CTRL>
__device__ __forceinline__ int dpp_i(int x, int old){
    return __builtin_amdgcn_update_dpp(old, x, CTRL, 0xf, 0xf, false);
}
__device__ __forceinline__ float wave_max_f(float v){
    const int NEG = __float_as_int(-3.4e38f);
#define STEPM(C) { float o = __int_as_float(dpp_i<C>(__float_as_int(v), NEG)); v = fmaxf(v, o); }
    STEPM(0x111) STEPM(0x112) STEPM(0x114) STEPM(0x118) STEPM(0x142) STEPM(0x143)
#undef STEPM
    return __int_as_float(__builtin_amdgcn_readlane(__float_as_int(v), 63));
}
// argmax (value desc, index asc); returns winner lane, sets wv/wh. Exact under ties.
__device__ __forceinline__ int wave_argmax_l(float bv, int bh, float &wv, int &wh){
    float v = wave_max_f(bv);
    ull tie = __ballot(bv == v);
    int tl = __ffsll((long long)tie) - 1;
    int h = __builtin_amdgcn_readlane(bh, tl);
    if (__builtin_expect(__popcll(tie) > 1, 0)){
        ull m = tie & (tie - 1);
        while (m){
            int l2 = __ffsll((long long)m) - 1;
            int h2 = __builtin_amdgcn_readlane(bh, l2);
            if (h2 < h){ h = h2; tl = l2; }
            m &= m - 1;
        }
    }
    wv = v; wh = h; return tl;
}

// ---------------- k_prep ----------------
__global__ __launch_bounds__(1024) void k_prep(const float* __restrict__ image,
        int* __restrict__ boff, int* __restrict__ sidx, unsigned* __restrict__ anyv){
    __shared__ int s_start[Nn];
    __shared__ int s_c4[4][Tt];
    __shared__ int s_boff[Tt + 1];
    int tid = threadIdx.x;
    for (int i = tid; i < Nn; i += 1024)
        s_start[i] = (int)floorf(__fmul_rn(256.f, image[i]));
    if (tid < Tt) anyv[tid] = 0u;
    __syncthreads();
    int b = tid & 255, q = tid >> 8;
    {
        int c = 0;
        for (int k = 0; k < 1024; ++k) c += (s_start[q * 1024 + k] == b) ? 1 : 0;
        s_c4[q][b] = c;
    }
    __syncthreads();
    if (tid == 0){
        int acc = 0;
        for (int bb = 0; bb < Tt; ++bb){
            s_boff[bb] = acc;
            acc += s_c4[0][bb] + s_c4[1][bb] + s_c4[2][bb] + s_c4[3][bb];
        }
        s_boff[Tt] = acc;
    }
    __syncthreads();
    if (tid <= Tt) boff[tid] = s_boff[tid];
    int p = s_boff[b];
    if (q > 0) p += s_c4[0][b];
    if (q > 1) p += s_c4[1][b];
    if (q > 2) p += s_c4[2][b];
    for (int k = 0; k < 1024; ++k){
        int i = q * 1024 + k;
        if (s_start[i] == b) sidx[p++] = i;
    }
}

// ---------------- k_gbuckets ----------------
__global__ __launch_bounds__(256) void k_gbuckets(const float* __restrict__ W1,
        const int* __restrict__ boff, const int* __restrict__ sidx,
        float* __restrict__ G_T){
    __shared__ float rows[4][Nn];
    int tid = threadIdx.x;
    int h0 = blockIdx.x * 4;
    for (int r = 0; r < 4; ++r){
        const float4* src = (const float4*)(W1 + (size_t)(h0 + r) * Nn);
        float4* dst = (float4*)rows[r];
        for (int j = tid; j < Nn / 4; j += 256) dst[j] = src[j];
    }
    __syncthreads();
    int t = tid;
    int b0 = boff[t], b1 = boff[t + 1];
    float s0 = 0.f, s1 = 0.f, s2 = 0.f, s3 = 0.f;
    for (int k = b0; k < b1; ++k){
        int i = sidx[k];
        s0 += rows[0][i]; s1 += rows[1][i]; s2 += rows[2][i]; s3 += rows[3][i];
    }
    G_T[(size_t)(h0 + 0) * Tt + t] = s0;
    G_T[(size_t)(h0 + 1) * Tt + t] = s1;
    G_T[(size_t)(h0 + 2) * Tt + t] = s2;
    G_T[(size_t)(h0 + 3) * Tt + t] = s3;
}

// ---------------- k_c1M ----------------
__global__ __launch_bounds__(256) void k_c1M(const float* __restrict__ G_T,
        float* __restrict__ c1T, float* __restrict__ M,
        float* __restrict__ r1pre, float* __restrict__ o_r1){
    __shared__ float tile[32][Tt + 1];
    __shared__ float c1s[32][Tt + 1];
    const int tid = threadIdx.x;
    const int h0 = blockIdx.x * 32;
    for (int r = 0; r < 32; ++r) tile[r][tid] = G_T[(size_t)(h0 + r) * Tt + tid];
    __syncthreads();
    {
        int hs = tid & 31, ts = tid >> 5;
        for (int tb = 0; tb < 32; ++tb){
            int t = tb * 8 + ts;
            int lo = (t - 7 < 0) ? 0 : t - 7;
            float s = 0.f;
            for (int u = lo; u <= t; ++u) s += tile[hs][u];
            c1s[hs][t] = s;
        }
    }
    __syncthreads();
    if (tid < 32){
        float m = 0.f;
        for (int t = 0; t < Tt; ++t){
            m = __fadd_rn(__fmul_rn(0.9f, m), c1s[tid][t]);
            M[(size_t)t * Hn + h0 + tid] = m;
        }
        r1pre[h0 + tid] = 0.f;
        o_r1[h0 + tid] = 256.f;
    }
    {
        int hr = tid >> 3, qq = tid & 7;
        float* drow = c1T + (size_t)(h0 + hr) * Tt + qq * 32;
        for (int k = 0; k < 8; ++k){
            float4 v = make_float4(c1s[hr][qq*32 + 4*k], c1s[hr][qq*32 + 4*k + 1],
                                   c1s[hr][qq*32 + 4*k + 2], c1s[hr][qq*32 + 4*k + 3]);
            ((float4*)drow)[k] = v;
        }
    }
}

// ---------------- k_sel: rank-CAP radix select; cand = (val, idxbits, te_eff, vcap) ----------------
// idxbits: idx | fire<<14 | valid<<15
__global__ __launch_bounds__(256) void k_sel(const float* __restrict__ M,
        const float* __restrict__ thr1, float4* __restrict__ cand){
    const int t = blockIdx.x, tid = threadIdx.x;
    __shared__ float s_row[Hn];
    __shared__ unsigned s_hist[256];
    __shared__ unsigned s_suf[256];
    __shared__ unsigned s_pref;
    __shared__ int s_rank;
    __shared__ int s_cnt;
    __shared__ int s_idx[CAP + 64];
    {
        const float4* src = (const float4*)(M + (size_t)t * Hn);
        float4* d4 = (float4*)s_row;
        for (int j = tid; j < Hn / 4; j += 256) d4[j] = src[j];
    }
    if (tid == 0){ s_pref = 0u; s_rank = CAP; s_cnt = 0; }
    __syncthreads();
#pragma unroll
    for (int b = 3; b >= 0; --b){
        s_hist[tid] = 0u;
        __syncthreads();
        unsigned pref = s_pref;
        int r = s_rank;
        for (int k = 0; k < 32; ++k){
            unsigned u = __float_as_uint(s_row[tid + (k << 8)]);
            bool match = (b == 3) ? true : ((u >> ((b + 1) * 8)) == pref);
            if (match) atomicAdd(&s_hist[(u >> (b * 8)) & 255], 1u);
        }
        __syncthreads();
        s_suf[tid] = s_hist[tid];
        __syncthreads();
#pragma unroll
        for (int off = 1; off < 256; off <<= 1){
            unsigned v = (tid + off < 256) ? s_suf[tid + off] : 0u;
            __syncthreads();
            s_suf[tid] += v;
            __syncthreads();
        }
        unsigned above = s_suf[tid] - s_hist[tid];
        if ((int)above < r && r <= (int)s_suf[tid]){
            s_pref = (pref << 8) | (unsigned)tid;
            s_rank = r - (int)above;
        }
        __syncthreads();
    }
    unsigned V = s_pref;
    for (int k = 0; k < 32; ++k){
        int i = tid + (k << 8);
        unsigned u = __float_as_uint(s_row[i]);
        if (u >= V){
            int p = atomicAdd(&s_cnt, 1);
            if (p < CAP + 64) s_idx[p] = i;
        }
    }
    __syncthreads();
    int c = s_cnt;
    bool ovf = (c > CAP);
    float vV = __uint_as_float(V);
    for (int i = tid; i < CAP; i += 256){
        float4 e;
        if (ovf){
            e = make_float4(-2.f, 0.f, 0.f, 3.4e38f);
        } else if (i < c){
            int ix = s_idx[i];
            float v = s_row[ix];
            float te = th_lazy2(thr1[ix], 150.f, 400.f, t);
            int mi = ix | ((v > te) ? (1 << 14) : 0) | (1 << 15);
            e = make_float4(v, __int_as_float(mi), te, vV);
        } else {
            e = make_float4(-1.f, 0.f, 0.f, vV);
        }
        cand[(size_t)t * CAP + i] = e;
    }
}

// ---------------- k_fused: block0 = serial WTA; other blocks = W1 bulk, W2 copy, W3T ----------------
#define NB_W1 1024
#define NB_W2 1024
#define NB_W3T 128

__global__ __launch_bounds__(256, 1) void k_fused(
        const float* __restrict__ M, const float* __restrict__ c1T,
        const float4* __restrict__ cand, const float* __restrict__ thr1,
        const float* __restrict__ W1, const float* __restrict__ W2,
        const float* __restrict__ W3,
        float* __restrict__ o_W1, float* __restrict__ o_W2, float* __restrict__ W3T,
        float* __restrict__ r1pre, float* __restrict__ o_r1,
        int* __restrict__ j1s, int* __restrict__ mh, int* __restrict__ nRout){
    __shared__ float tl[64][65];
    __shared__ unsigned s_bitw[Hn / 32];
    const int bid = blockIdx.x;
    const int tid = threadIdx.x;

    if (bid >= 1 && bid < 1 + NB_W1){
        // W1 bulk: o_W1 = W1 + 0.01 (non-fired-row formula)
        size_t base = (size_t)(bid - 1) * 8192;
        const float4* src = (const float4*)W1;
        float4* dst = (float4*)o_W1;
        for (int i = tid; i < 8192; i += 256){
            float4 s = src[base + i];
            s.x = __fadd_rn(s.x, 0.01f); s.y = __fadd_rn(s.y, 0.01f);
            s.z = __fadd_rn(s.z, 0.01f); s.w = __fadd_rn(s.w, 0.01f);
            dst[base + i] = s;
        }
        return;
    }
    if (bid >= 1 + NB_W1 && bid < 1 + NB_W1 + NB_W2){
        // W2 bulk: o_W2 = clamp01(W2) == W2 (identity for zeta=0 columns)
        size_t base = (size_t)(bid - 1 - NB_W1) * 8192;
        const float4* src = (const float4*)W2;
        float4* dst = (float4*)o_W2;
        for (int i = tid; i < 8192; i += 256){
            float4 s = src[base + i];
            s.x = clamp01(s.x); s.y = clamp01(s.y);
            s.z = clamp01(s.z); s.w = clamp01(s.w);
            dst[base + i] = s;
        }
        return;
    }
    if (bid >= 1 + NB_W1 + NB_W2){
        // W3T transpose
        int r = bid - 1 - NB_W1 - NB_W2;
        int bx = r & 63, by = r >> 6;
        int n0 = bx * 64, c0 = by * 64;
        for (int e = tid; e < 64 * 64; e += 256){
            int rr = e >> 6, cc = e & 63;
            tl[rr][cc] = W3[(size_t)(c0 + rr) * Nn + n0 + cc];
        }
        __syncthreads();
        for (int e = tid; e < 64 * 64; e += 256){
            int rn = e >> 6, cc = e & 63;
            W3T[(size_t)(n0 + rn) * Cn + c0 + cc] = tl[cc][rn];
        }
        return;
    }

    // ---- block 0: serial WTA on wave 0 ----
    if (tid >= 64) return;
    const int lane = tid;
    for (int i = lane; i < Hn / 32; i += 64) s_bitw[i] = 0u;

    int   sh0=-1,sh1=-1,sh2=-1,sh3=-1;
    float sm0=0.f,sm1=0.f,sm2=0.f,sm3=0.f;
    float st0=0.f,st1=0.f,st2=0.f,st3=0.f;
    int   ss0=0,ss1=0,ss2=0,ss3=0;
    float sr0=0.f,sr1=0.f,sr2=0.f,sr3=0.f;
    float4 z4 = make_float4(0.f,0.f,0.f,0.f);
    float4 dA0=z4,dA1=z4,dA2=z4,dA3=z4,dB0=z4,dB1=z4,dB2=z4,dB3=z4;
    int nR = 0;

    float4 cA0 = cand[lane],         cA1 = cand[64 + lane],         cA2 = cand[128 + lane];
    float4 cB0 = cand[CAP + lane],   cB1 = cand[CAP + 64 + lane],   cB2 = cand[CAP + 128 + lane];
    float4 cC0 = cand[2*CAP + lane], cC1 = cand[2*CAP + 64 + lane], cC2 = cand[2*CAP + 128 + lane];
    int mb0 = 0, mb1 = 0, mb2 = 0;

#define UPDX(i, JJ) if (sh##i >= 0){ \
        float dv = (JJ==0)?dA##i.x:(JJ==1)?dA##i.y:(JJ==2)?dA##i.z:dA##i.w; \
        sm##i = __fadd_rn(__fmul_rn(0.9f, sm##i), dv); \
        if (sm##i > bv || (sm##i == bv && sh##i < bh)){ bv = sm##i; bh = sh##i; pay = 0; } }

#define CMERGE(c) { \
        int mc = __float_as_int(cA##c.y); \
        int ic = mc & 8191; \
        int nm = ((mc >> 15) & 1) & (mb##c ^ 1); \
        annm |= nm; \
        if (nm && (cA##c.x > bv || (cA##c.x == bv && ic < bh))){ \
            bv = cA##c.x; bh = ic; pay = 2 | ((mc >> 14) & 1); bte = cA##c.z; } }

#define STEPX(JJ) { \
        const int t = (g << 2) + JJ; \
        float bv = -3.4e38f; int bh = 0x7FFFFFFF; int pay = 0; float bte = 0.f; int annm = 0; \
        UPDX(0,JJ) UPDX(1,JJ) UPDX(2,JJ) UPDX(3,JJ) \
        CMERGE(0) CMERGE(1) CMERGE(2) \
        ull anyNM = __ballot(annm); \
        float wv; int wh; \
        int wl = wave_argmax_l(bv, bh, wv, wh); \
        int pw = __builtin_amdgcn_readlane(pay, wl); \
        float tw = __int_as_float(__builtin_amdgcn_readlane(__float_as_int(bte), wl)); \
        const float vc = cA0.w; \
        int didFB = 0, skip = 0; \
        if (anyNM == 0ull){ \
            if (wv >= vc){ \
            } else if (t > 0 && vc < 150.f){ skip = 1; } \
            else { \
                float fv = -3.4e38f; int fh = 0x7FFFFFFF; \
                if (sh0 >= 0 && (sm0 > fv || (sm0 == fv && sh0 < fh))){ fv = sm0; fh = sh0; } \
                if (sh1 >= 0 && (sm1 > fv || (sm1 == fv && sh1 < fh))){ fv = sm1; fh = sh1; } \
                if (sh2 >= 0 && (sm2 > fv || (sm2 == fv && sh2 < fh))){ fv = sm2; fh = sh2; } \
                if (sh3 >= 0 && (sm3 > fv || (sm3 == fv && sh3 < fh))){ fv = sm3; fh = sh3; } \
                const float4* Mrow4 = (const float4*)(M + (size_t)t * Hn); \
                for (int q2 = 0; q2 < 32; ++q2){ \
                    int e = q2 * 64 + lane; \
                    float4 mv = Mrow4[e]; \
                    int ib = e * 4; \
                    unsigned wb = s_bitw[ib >> 5]; \
                    if (!((wb >> ((ib+0) & 31)) & 1u) && (mv.x > fv || (mv.x == fv && ib+0 < fh))){ fv = mv.x; fh = ib+0; } \
                    if (!((wb >> ((ib+1) & 31)) & 1u) && (mv.y > fv || (mv.y == fv && ib+1 < fh))){ fv = mv.y; fh = ib+1; } \
                    if (!((wb >> ((ib+2) & 31)) & 1u) && (mv.z > fv || (mv.z == fv && ib+2 < fh))){ fv = mv.z; fh = ib+2; } \
                    if (!((wb >> ((ib+3) & 31)) & 1u) && (mv.w > fv || (mv.w == fv && ib+3 < fh))){ fv = mv.w; fh = ib+3; } \
                } \
                wave_argmax_l(fv, fh, wv, wh); \
                didFB = 1; \
            } \
        } \
        if (!skip){ \
            int m0=(sh0==wh), m1=(sh1==wh), m2=(sh2==wh), m3=(sh3==wh); \
            ull memMask = __ballot(m0 | m1 | m2 | m3); \
            if (memMask != 0ull){ \
                int fflag = 0, jsl = -1; \
                if (m0){ float te = th_lazy2(st0, 150.f, 400.f, t - ss0 - 1); if (wv > te){ fflag=1; sm0=0.f; st0=fminf(fmaxf(__fadd_rn(__fsub_rn(te,0.05f),5.0f),150.f),400.f); ss0=t; jsl=lane; } } \
                if (m1){ float te = th_lazy2(st1, 150.f, 400.f, t - ss1 - 1); if (wv > te){ fflag=1; sm1=0.f; st1=fminf(fmaxf(__fadd_rn(__fsub_rn(te,0.05f),5.0f),150.f),400.f); ss1=t; jsl=64+lane; } } \
                if (m2){ float te = th_lazy2(st2, 150.f, 400.f, t - ss2 - 1); if (wv > te){ fflag=1; sm2=0.f; st2=fminf(fmaxf(__fadd_rn(__fsub_rn(te,0.05f),5.0f),150.f),400.f); ss2=t; jsl=128+lane; } } \
                if (m3){ float te = th_lazy2(st3, 150.f, 400.f, t - ss3 - 1); if (wv > te){ fflag=1; sm3=0.f; st3=fminf(fmaxf(__fadd_rn(__fsub_rn(te,0.05f),5.0f),150.f),400.f); ss3=t; jsl=192+lane; } } \
                ull fm = __ballot(fflag); \
                if (fm != 0ull){ if (fflag) j1s[t] = jsl; } \
                else if (lane == 0) j1s[t] = -1; \
            } else { \
                float te_b = didFB ? th_lazy2(thr1[wh], 150.f, 400.f, t) : tw; \
                int fire = didFB ? ((wv > te_b) ? 1 : 0) : (pw & 1); \
                if (fire){ \
                    float thnew = fminf(fmaxf(__fadd_rn(__fsub_rn(te_b,0.05f),5.0f),150.f),400.f); \
                    if (lane == (nR & 63)){ \
                        const float4* crow = (const float4*)(c1T + (size_t)wh * Tt); \
                        int g1 = (g + 1 < 64) ? g + 1 : 63; \
                        int srg = nR >> 6; \
                        if (srg == 0){ sh0=wh; sm0=0.f; st0=thnew; ss0=t; sr0=(float)(t+1); dA0=crow[g]; dB0=crow[g1]; } \
                        else if (srg == 1){ sh1=wh; sm1=0.f; st1=thnew; ss1=t; sr1=(float)(t+1); dA1=crow[g]; dB1=crow[g1]; } \
                        else if (srg == 2){ sh2=wh; sm2=0.f; st2=thnew; ss2=t; sr2=(float)(t+1); dA2=crow[g]; dB2=crow[g1]; } \
                        else { sh3=wh; sm3=0.f; st3=thnew; ss3=t; sr3=(float)(t+1); dA3=crow[g]; dB3=crow[g1]; } \
                        j1s[t] = nR; \
                        mh[nR] = wh; \
                    } \
                    if (lane == 0) atomicOr(&s_bitw[wh >> 5], 1u << (wh & 31)); \
                    nR++; \
                } else { \
                    if (lane == 0) j1s[t] = -1; \
                } \
            } \
        } else { \
            if (lane == 0) j1s[t] = -1; \
        } \
        /* rotate candidates; membership read AFTER join (same-wave DS order) */ \
        { \
            int n0i = __float_as_int(cB0.y) & 8191; \
            int n1i = __float_as_int(cB1.y) & 8191; \
            int n2i = __float_as_int(cB2.y) & 8191; \
            mb0 = (int)((s_bitw[n0i >> 5] >> (n0i & 31)) & 1u); \
            mb1 = (int)((s_bitw[n1i >> 5] >> (n1i & 31)) & 1u); \
            mb2 = (int)((s_bitw[n2i >> 5] >> (n2i & 31)) & 1u); \
            cA0 = cB0; cA1 = cB1; cA2 = cB2; \
            cB0 = cC0; cB1 = cC1; cB2 = cC2; \
            int tn = (t + 3 < Tt) ? t + 3 : Tt - 1; \
            cC0 = cand[(size_t)tn * CAP + lane]; \
            cC1 = cand[(size_t)tn * CAP + 64 + lane]; \
            cC2 = cand[(size_t)tn * CAP + 128 + lane]; \
        } \
    }

    for (int g = 0; g < 64; ++g){
        STEPX(0)
        STEPX(1)
        STEPX(2)
        STEPX(3)
        if (g < 63){
            int g2 = (g + 2 < 64) ? g + 2 : 63;
            dA0 = dB0; if (sh0 >= 0) dB0 = ((const float4*)(c1T + (size_t)sh0 * Tt))[g2];
            dA1 = dB1; if (sh1 >= 0) dB1 = ((const float4*)(c1T + (size_t)sh1 * Tt))[g2];
            dA2 = dB2; if (sh2 >= 0) dB2 = ((const float4*)(c1T + (size_t)sh2 * Tt))[g2];
            dA3 = dB3; if (sh3 >= 0) dB3 = ((const float4*)(c1T + (size_t)sh3 * Tt))[g2];
        }
    }
#undef STEPX
#undef CMERGE
#undef UPDX
    if (sh0 >= 0){ r1pre[sh0] = sr0; o_r1[sh0] = sr0; }
    if (sh1 >= 0){ r1pre[sh1] = sr1; o_r1[sh1] = sr1; }
    if (sh2 >= 0){ r1pre[sh2] = sr2; o_r1[sh2] = sr2; }
    if (sh3 >= 0){ r1pre[sh3] = sr3; o_r1[sh3] = sr3; }
    if (lane == 0) *nRout = nR;
}

// ---------------- k_colg ----------------
__global__ __launch_bounds__(256) void k_colg(const float* __restrict__ W2,
        const int* __restrict__ mh, const int* __restrict__ nRout,
        float* __restrict__ colv){
    int slot = blockIdx.x;
    if (slot >= *nRout) return;
    int h = mh[slot];
    int tid = threadIdx.x;
    float* dst = colv + (size_t)slot * Nn;
    for (int n = tid; n < Nn; n += 256) dst[n] = W2[(size_t)n * Hn + h];
}

// ---------------- k_lif2 ----------------
__global__ __launch_bounds__(64) void k_lif2(const float* __restrict__ colv,
        const int* __restrict__ j1s, const float* __restrict__ thr2,
        float* __restrict__ o_r2, ull* __restrict__ spkb, unsigned* __restrict__ anyv){
    __shared__ int s_j[Tt];
    int lane = threadIdx.x, blk = blockIdx.x;
    for (int i = lane; i < Tt; i += 64) s_j[i] = j1s[i];
    __syncthreads();
    int n = blk * 64 + lane;
    float tv = thr2[n], m = 0.f, rp = 0.f;
    for (int t = 0; t < Tt; ++t){
        int s = s_j[t];
        float u = (s >= 0) ? colv[(size_t)s * Nn + n] : 0.f;
        m = __fadd_rn(__fmul_rn(0.8f, m), u);
        int f = 0;
        if (m > tv){
            m = __fsub_rn(m, tv);
            if (rp == 0.f) rp = (float)(t + 1);
            f = 1;
        }
        ull mask = __ballot(f);
        if (lane == 0){
            spkb[t * 64 + blk] = mask;
            if (mask) atomicOr(&anyv[t], 1u);
        }
    }
    o_r2[n] = (rp == 0.f) ? 256.f : rp;
}

// ---------------- k_sim3 ----------------
__global__ __launch_bounds__(128, 1) void k_sim3(const ull* __restrict__ spkb,
        const unsigned* __restrict__ anyv, const float* __restrict__ W3T,
        const float* __restrict__ thr3, float* __restrict__ o_r3){
    int tid = threadIdx.x, lane = tid & 63, w = tid >> 6;
    __shared__ unsigned s_any[Tt];
    __shared__ ull s_r2[2];
    __shared__ int s_fire;
    for (int i = tid; i < Tt; i += 128) s_any[i] = anyv[i];
    float m = 0.f, th0 = thr3[tid], rp = 0.f, thv = 0.f;
    int ts = -1, zero = 1;
    __syncthreads();
    for (int t = 0; t < Tt; ++t){
        if (zero && s_any[t] == 0u) continue;
        float d = 0.f;
        if (s_any[t]){
            for (int ww = 0; ww < 64; ++ww){
                ull bits = spkb[t * 64 + ww];
                while (bits){
                    int b2 = __ffsll((long long)bits) - 1;
                    bits &= bits - 1;
                    d = __fadd_rn(d, W3T[(size_t)(ww * 64 + b2) * Cn + tid]);
                }
            }
        }
        m = __fadd_rn(__fmul_rn(0.9f, m), d);
        ull k = (((ull)__float_as_uint(m >= 0.f ? m : 0.f)) << 32) | (unsigned)(8191 - tid);
        if (!(m >= 0.f)) k = (unsigned)(8191 - tid);
#pragma unroll
        for (int off = 32; off >= 1; off >>= 1){
            ull o = __shfl_down(k, off);
            if (o > k) k = o;
        }
        if (lane == 0) s_r2[w] = k;
        __syncthreads();
        ull wk = s_r2[0] > s_r2[1] ? s_r2[0] : s_r2[1];
        int wc = 8191 - (int)(wk & 0xFFFFu);
        float wv = __uint_as_float((unsigned)(wk >> 32));
        if (tid == wc){
            float te = (ts < 0) ? th_lazy2(th0, 50.f, 200.f, t)
                                : th_lazy2(thv, 50.f, 200.f, t - ts - 1);
            int f = (wv > te) ? 1 : 0;
            s_fire = f;
            if (f){
                thv = fminf(fmaxf(__fadd_rn(__fsub_rn(te, 0.05f), 5.0f), 50.f), 200.f);
                ts = t;
                if (rp == 0.f) rp = (float)(t + 1);
            }
        }
        __syncthreads();
        if (s_fire){ m = 0.f; zero = 1; }
        else zero = 0;
        __syncthreads();
    }
    o_r3[tid] = (rp == 0.f) ? 256.f : rp;
}

// ---------------- k_scalars ----------------
__global__ __launch_bounds__(1024) void k_scalars(const float* __restrict__ image,
        const float* __restrict__ r1pre, const float* __restrict__ o_r1,
        const float* __restrict__ o_r2,
        float* __restrict__ zeta, float* __restrict__ rho,
        float* __restrict__ imgt, float* __restrict__ eiP, float* __restrict__ eiM,
        float* __restrict__ Pv, float* __restrict__ Qv,
        float* __restrict__ E2P, float* __restrict__ E2M,
        float* __restrict__ o_err, float* __restrict__ o_es){
    int tid = threadIdx.x;
    for (int h = tid; h < Hn; h += 1024){
        float r1f = o_r1[h];
        float mask = (r1pre[h] != 0.f) ? 1.f : 0.f;
        float z = __fmul_rn(__fmul_rn(__fsub_rn(256.f, r1f), mask), 0.00390625f);
        zeta[h] = z;
        Pv[h] = __expf(r1f * 0.05f) * z;
        Qv[h] = __expf(-r1f * 0.05f) * z;
    }
    float acc = 0.f;
    for (int n = tid; n < Nn; n += 1024){
        float img = __fmul_rn(256.f, image[n]);
        float r2f = o_r2[n];
        float e = __fmul_rn(__fsub_rn(img, __fsub_rn(r2f, 4.0f)), 0.00390625f);
        o_err[n] = e;
        rho[n] = __fadd_rn(__fmul_rn(__fsub_rn(__fsub_rn(r2f, 4.0f), img), 0.00390625f), 0.15f);
        imgt[n] = img;
        eiP[n] = __expf(img * 0.05f);
        eiM[n] = __expf(-img * 0.05f);
        E2P[n] = __expf(r2f * 0.05f);
        E2M[n] = __expf(-r2f * 0.05f);
        acc = __fadd_rn(acc, __fmul_rn(e, e));
    }
    __shared__ float red[16];
    for (int off = 32; off >= 1; off >>= 1) acc += __shfl_down(acc, off);
    int lane = tid & 63, w = tid >> 6;
    if (lane == 0) red[w] = acc;
    __syncthreads();
    if (tid == 0){
        float s = 0.f;
        for (int q = 0; q < 16; ++q) s += red[q];
        *o_es = s;
    }
}

// ---------------- k_w1fix: rewrite fired rows with STDP formula ----------------
__global__ __launch_bounds__(256) void k_w1fix(const float* __restrict__ W1,
        const float* __restrict__ imgt, const float* __restrict__ eiP,
        const float* __restrict__ eiM, const float* __restrict__ o_r1,
        const int* __restrict__ mh, const int* __restrict__ nRout,
        float* __restrict__ o_W1){
    int slot = blockIdx.x;
    if (slot >= *nRout) return;
    int h = mh[slot];
    int tid = threadIdx.x;
    float r1f = o_r1[h];
    float a = 0.01f * __expf(-r1f * 0.05f);
    float b = 0.01f * __expf( r1f * 0.05f);
    const float4* src = (const float4*)(W1 + (size_t)h * Nn);
    float4* dst = (float4*)(o_W1 + (size_t)h * Nn);
    const float4* ig = (const float4*)imgt;
    const float4* p4 = (const float4*)eiP;
    const float4* m4 = (const float4*)eiM;
    for (int i = tid; i < Nn / 4; i += 256){
        float4 s = src[i];
        float4 im = ig[i], pp = p4[i], mm = m4[i];
        s.x += (r1f >= im.x) ? a * pp.x : -(b * mm.x);
        s.y += (r1f >= im.y) ? a * pp.y : -(b * mm.y);
        s.z += (r1f >= im.z) ? a * pp.z : -(b * mm.z);
        s.w += (r1f >= im.w) ? a * pp.w : -(b * mm.w);
        dst[i] = s;
    }
}

// ---------------- k_w2fix: patch member columns of o_W2 ----------------
__global__ __launch_bounds__(128) void k_w2fix(
        const float* __restrict__ o_r1, const float* __restrict__ Pv,
        const float* __restrict__ Qv, const float* __restrict__ o_r2,
        const float* __restrict__ rho, const int* __restrict__ mh,
        const int* __restrict__ nRout, float* __restrict__ o_W2){
    __shared__ int   s_h[Tt];
    __shared__ float s_rv[Tt], s_pp[Tt], s_qq[Tt];
    int n = blockIdx.x, tid = threadIdx.x;
    int nRv = *nRout;
    for (int s = tid; s < nRv; s += 128){
        int h = mh[s];
        s_h[s] = h; s_rv[s] = o_r1[h]; s_pp[s] = Pv[h]; s_qq[s] = Qv[h];
    }
    __syncthreads();
    float r2f = o_r2[n], rh = rho[n];
    float A = 0.01f * rh * __expf(-r2f * 0.05f);
    float B = 0.01f * rh * __expf( r2f * 0.05f);
    for (int s = tid; s < nRv; s += 128){
        size_t idx = (size_t)n * Hn + s_h[s];
        float w = o_W2[idx];
        float rv = s_rv[s];
        w = clamp01(w + ((r2f >= rv) ? A * s_pp[s] : -(B * s_qq[s])));
        o_W2[idx] = w;
    }
}

// ---------------- k_w3new ----------------
__global__ __launch_bounds__(256) void k_w3new(const float* __restrict__ W3,
        const float* __restrict__ o_r2, const float* __restrict__ E2P,
        const float* __restrict__ E2M, const float* __restrict__ o_r3,
        float* __restrict__ o_W3){
    int c = blockIdx.x, tid = threadIdx.x;
    float r3f = o_r3[c];
    float a = 0.01f * __expf(-r3f * 0.05f);
    float b = 0.01f * __expf( r3f * 0.05f);
    const float4* src = (const float4*)(W3 + (size_t)c * Nn);
    float4* dst = (float4*)(o_W3 + (size_t)c * Nn);
    const float4* r24 = (const float4*)o_r2;
    const float4* p4 = (const float4*)E2P;
    const float4* m4 = (const float4*)E2M;
    for (int i = tid; i < Nn / 4; i += 256){
        float4 s = src[i]; float4 rv = r24[i]; float4 pp = p4[i]; float4 mm = m4[i];
        s.x += (r3f >= rv.x) ? a * pp.x : -(b * mm.x);
        s.y += (r3f >= rv.y) ? a * pp.y : -(b * mm.y);
        s.z += (r3f >= rv.z) ? a * pp.z : -(b * mm.z);
        s.w += (r3f >= rv.w) ? a * pp.w : -(b * mm.w);
        dst[i] = s;
    }
}

extern "C" void kernel_launch(void* const* d_in, const int* in_sizes, int n_in,
                              void* d_out, int out_size, void* d_ws, size_t ws_size,
                              hipStream_t stream){
    const float* image = (const float*)d_in[0];
    const float* W1   = (const float*)d_in[1];
    const float* W2   = (const float*)d_in[2];
    const float* W3   = (const float*)d_in[3];
    const float* thr1 = (const float*)d_in[4];
    const float* thr2 = (const float*)d_in[5];
    const float* thr3 = (const float*)d_in[6];

    float* out  = (float*)d_out;
    float* o_err = out;
    float* o_es  = out + 4096;
    float* o_r1  = out + 4097;
    float* o_r2  = out + 12289;
    float* o_r3  = out + 16385;
    float* o_W1  = out + 16513;
    float* o_W2  = o_W1 + (size_t)Hn * Nn;
    float* o_W3  = o_W2 + (size_t)Nn * Hn;

    float* ws = (float*)d_ws;
    float* G_T   = ws;
    float* c1T   = G_T + (size_t)Hn * Tt;
    float* M     = c1T + (size_t)Hn * Tt;
    float* W3T   = M + (size_t)Tt * Hn;
    float* colv  = W3T + (size_t)Nn * Cn;
    float4* cand = (float4*)(colv + (size_t)256 * Nn);
    ull* spkb    = (ull*)(cand + (size_t)Tt * CAP);
    float* r1pre = (float*)(spkb + (size_t)Tt * 64);
    float* zeta  = r1pre + Hn;
    float* rho   = zeta + Hn;
    float* imgt  = rho + Nn;
    float* eiP   = imgt + Nn;
    float* eiM   = eiP + Nn;
    float* Pv    = eiM + Nn;
    float* Qv    = Pv + Hn;
    float* E2P   = Qv + Hn;
    float* E2M   = E2P + Nn;
    int* boff  = (int*)(E2M + Nn);
    int* sidx  = boff + (Tt + 1);
    int* j1s   = sidx + Nn;
    int* mh    = j1s + Tt;
    int* nRout = mh + 256;
    unsigned* anyv = (unsigned*)(nRout + 1);

    k_prep<<<1, 1024, 0, stream>>>(image, boff, sidx, anyv);
    k_gbuckets<<<Hn / 4, 256, 0, stream>>>(W1, boff, sidx, G_T);
    k_c1M<<<Hn / 32, 256, 0, stream>>>(G_T, c1T, M, r1pre, o_r1);
    k_sel<<<Tt, 256, 0, stream>>>(M, thr1, cand);
    k_fused<<<1 + NB_W1 + NB_W2 + NB_W3T, 256, 0, stream>>>(
        M, c1T, cand, thr1, W1, W2, W3, o_W1, o_W2, W3T,
        r1pre, o_r1, j1s, mh, nRout);
    k_colg<<<256, 256, 0, stream>>>(W2, mh, nRout, colv);
    k_lif2<<<Nn / 64, 64, 0, stream>>>(colv, j1s, thr2, o_r2, spkb, anyv);
    k_sim3<<<1, 128, 0, stream>>>(spkb, anyv, W3T, thr3, o_r3);
    k_scalars<<<1, 1024, 0, stream>>>(image, r1pre, o_r1, o_r2, zeta, rho,
                                      imgt, eiP, eiM, Pv, Qv, E2P, E2M, o_err, o_es);
    k_w1fix<<<256, 256, 0, stream>>>(W1, imgt, eiP, eiM, o_r1, mh, nRout, o_W1);
    k_w2fix<<<Nn, 128, 0, stream>>>(o_r1, Pv, Qv, o_r2, rho, mh, nRout, o_W2);
    k_w3new<<<Cn, 256, 0, stream>>>(W3, o_r2, E2P, E2M, o_r3, o_W3);
}

// Round 10
// 567.200 us; speedup vs baseline: 1.4831x; 1.4250x over previous
//
#include <hip/hip_runtime.h>
#include <cstdint>
#include <cstddef>

#define Hn 8192
#define Nn 4096
#define Cn 128
#define Tt 256
#define CAP 192

typedef unsigned long long ull;

// th after nup clip-updates (decay -0.05 each) from base b, clamped [lo,hi]
__device__ __forceinline__ float th_lazy2(float b, float lo, float hi, int nup){
    if (nup <= 0) return b;
    float a = fminf(fmaxf(__fsub_rn(b, 0.05f), lo), hi);
    if (nup == 1) return a;
    return fmaxf(__fsub_rn(a, __fmul_rn(0.05f, (float)(nup - 1))), lo);
}

__device__ __forceinline__ float clamp01(float v){
    return fminf(fmaxf(v, 0.f), 1.f);
}

// ---- DPP cross-lane reduce (VALU pipe) ----
template<int CTRL>
__device__ __forceinline__ int dpp_i(int x, int old){
    return __builtin_amdgcn_update_dpp(old, x, CTRL, 0xf, 0xf, false);
}
__device__ __forceinline__ float wave_max_f(float v){
    const int NEG = __float_as_int(-3.4e38f);
#define STEPM(C) { float o = __int_as_float(dpp_i<C>(__float_as_int(v), NEG)); v = fmaxf(v, o); }
    STEPM(0x111) STEPM(0x112) STEPM(0x114) STEPM(0x118) STEPM(0x142) STEPM(0x143)
#undef STEPM
    return __int_as_float(__builtin_amdgcn_readlane(__float_as_int(v), 63));
}
// argmax (value desc, index asc); returns winner lane, sets wv/wh.
__device__ __forceinline__ int wave_argmax_l(float bv, int bh, float &wv, int &wh){
    float v = wave_max_f(bv);
    ull tie = __ballot(bv == v);
    int tl = __ffsll((long long)tie) - 1;
    int h = __builtin_amdgcn_readlane(bh, tl);
    if (__builtin_expect(__popcll(tie) > 1, 0)){
        ull m = tie & (tie - 1);
        while (m){
            int l2 = __ffsll((long long)m) - 1;
            int h2 = __builtin_amdgcn_readlane(bh, l2);
            if (h2 < h){ h = h2; tl = l2; }
            m &= m - 1;
        }
    }
    wv = v; wh = h; return tl;
}
__device__ __forceinline__ float rl_f(float x, int l){
    return __int_as_float(__builtin_amdgcn_readlane(__float_as_int(x), l));
}

// ---------------- k_prep ----------------
__global__ __launch_bounds__(1024) void k_prep(const float* __restrict__ image,
        int* __restrict__ boff, int* __restrict__ sidx, unsigned* __restrict__ anyv){
    __shared__ int s_start[Nn];
    __shared__ int s_c4[4][Tt];
    __shared__ int s_boff[Tt + 1];
    int tid = threadIdx.x;
    for (int i = tid; i < Nn; i += 1024)
        s_start[i] = (int)floorf(__fmul_rn(256.f, image[i]));
    if (tid < Tt) anyv[tid] = 0u;
    __syncthreads();
    int b = tid & 255, q = tid >> 8;
    {
        int c = 0;
        for (int k = 0; k < 1024; ++k) c += (s_start[q * 1024 + k] == b) ? 1 : 0;
        s_c4[q][b] = c;
    }
    __syncthreads();
    if (tid == 0){
        int acc = 0;
        for (int bb = 0; bb < Tt; ++bb){
            s_boff[bb] = acc;
            acc += s_c4[0][bb] + s_c4[1][bb] + s_c4[2][bb] + s_c4[3][bb];
        }
        s_boff[Tt] = acc;
    }
    __syncthreads();
    if (tid <= Tt) boff[tid] = s_boff[tid];
    int p = s_boff[b];
    if (q > 0) p += s_c4[0][b];
    if (q > 1) p += s_c4[1][b];
    if (q > 2) p += s_c4[2][b];
    for (int k = 0; k < 1024; ++k){
        int i = q * 1024 + k;
        if (s_start[i] == b) sidx[p++] = i;
    }
}

// ---------------- k_gbuckets ----------------
__global__ __launch_bounds__(256) void k_gbuckets(const float* __restrict__ W1,
        const int* __restrict__ boff, const int* __restrict__ sidx,
        float* __restrict__ G_T){
    __shared__ float rows[4][Nn];
    int tid = threadIdx.x;
    int h0 = blockIdx.x * 4;
    for (int r = 0; r < 4; ++r){
        const float4* src = (const float4*)(W1 + (size_t)(h0 + r) * Nn);
        float4* dst = (float4*)rows[r];
        for (int j = tid; j < Nn / 4; j += 256) dst[j] = src[j];
    }
    __syncthreads();
    int t = tid;
    int b0 = boff[t], b1 = boff[t + 1];
    float s0 = 0.f, s1 = 0.f, s2 = 0.f, s3 = 0.f;
    for (int k = b0; k < b1; ++k){
        int i = sidx[k];
        s0 += rows[0][i]; s1 += rows[1][i]; s2 += rows[2][i]; s3 += rows[3][i];
    }
    G_T[(size_t)(h0 + 0) * Tt + t] = s0;
    G_T[(size_t)(h0 + 1) * Tt + t] = s1;
    G_T[(size_t)(h0 + 2) * Tt + t] = s2;
    G_T[(size_t)(h0 + 3) * Tt + t] = s3;
}

// ---------------- k_c1M: window-sum + M-scan + r1 init ----------------
__global__ __launch_bounds__(256) void k_c1M(const float* __restrict__ G_T,
        float* __restrict__ M, float* __restrict__ r1pre, float* __restrict__ o_r1){
    __shared__ float tile[32][Tt + 1];
    __shared__ float c1s[32][Tt + 1];
    const int tid = threadIdx.x;
    const int h0 = blockIdx.x * 32;
    for (int r = 0; r < 32; ++r) tile[r][tid] = G_T[(size_t)(h0 + r) * Tt + tid];
    __syncthreads();
    {
        int hs = tid & 31, ts = tid >> 5;
        for (int tb = 0; tb < 32; ++tb){
            int t = tb * 8 + ts;
            int lo = (t - 7 < 0) ? 0 : t - 7;
            float s = 0.f;
            for (int u = lo; u <= t; ++u) s += tile[hs][u];
            c1s[hs][t] = s;
        }
    }
    __syncthreads();
    if (tid < 32){
        float m = 0.f;
        for (int t = 0; t < Tt; ++t){
            m = __fadd_rn(__fmul_rn(0.9f, m), c1s[tid][t]);
            M[(size_t)t * Hn + h0 + tid] = m;
        }
        r1pre[h0 + tid] = 0.f;
        o_r1[h0 + tid] = 256.f;
    }
}

// ---------------- k_sel: rank-CAP radix select; cand = (val, idx|valid<<15, 0, vcap) ----------------
__global__ __launch_bounds__(256) void k_sel(const float* __restrict__ M,
        float4* __restrict__ cand){
    const int t = blockIdx.x, tid = threadIdx.x;
    __shared__ float s_row[Hn];
    __shared__ unsigned s_hist[256];
    __shared__ unsigned s_suf[256];
    __shared__ unsigned s_pref;
    __shared__ int s_rank;
    __shared__ int s_cnt;
    __shared__ int s_idx[CAP + 64];
    {
        const float4* src = (const float4*)(M + (size_t)t * Hn);
        float4* d4 = (float4*)s_row;
        for (int j = tid; j < Hn / 4; j += 256) d4[j] = src[j];
    }
    if (tid == 0){ s_pref = 0u; s_rank = CAP; s_cnt = 0; }
    __syncthreads();
#pragma unroll
    for (int b = 3; b >= 0; --b){
        s_hist[tid] = 0u;
        __syncthreads();
        unsigned pref = s_pref;
        int r = s_rank;
        for (int k = 0; k < 32; ++k){
            unsigned u = __float_as_uint(s_row[tid + (k << 8)]);
            bool match = (b == 3) ? true : ((u >> ((b + 1) * 8)) == pref);
            if (match) atomicAdd(&s_hist[(u >> (b * 8)) & 255], 1u);
        }
        __syncthreads();
        s_suf[tid] = s_hist[tid];
        __syncthreads();
#pragma unroll
        for (int off = 1; off < 256; off <<= 1){
            unsigned v = (tid + off < 256) ? s_suf[tid + off] : 0u;
            __syncthreads();
            s_suf[tid] += v;
            __syncthreads();
        }
        unsigned above = s_suf[tid] - s_hist[tid];
        if ((int)above < r && r <= (int)s_suf[tid]){
            s_pref = (pref << 8) | (unsigned)tid;
            s_rank = r - (int)above;
        }
        __syncthreads();
    }
    unsigned V = s_pref;
    for (int k = 0; k < 32; ++k){
        int i = tid + (k << 8);
        unsigned u = __float_as_uint(s_row[i]);
        if (u >= V){
            int p = atomicAdd(&s_cnt, 1);
            if (p < CAP + 64) s_idx[p] = i;
        }
    }
    __syncthreads();
    int c = s_cnt;
    bool ovf = (c > CAP);
    float vV = ovf ? 3.4e38f : __uint_as_float(V);
    for (int i = tid; i < CAP; i += 256){
        float4 e;
        if (!ovf && i < c){
            int ix = s_idx[i];
            e = make_float4(s_row[ix], __int_as_float(ix | (1 << 15)), 0.f, vV);
        } else {
            e = make_float4(-1.f, 0.f, 0.f, vV);
        }
        cand[(size_t)t * CAP + i] = e;
    }
}

// ---------------- k_w3t ----------------
__global__ __launch_bounds__(256) void k_w3t(const float* __restrict__ W3,
                                             float* __restrict__ W3T){
    __shared__ float tl[64][65];
    int bx = blockIdx.x & 63, by = blockIdx.x >> 6;
    int n0 = bx * 64, c0 = by * 64;
    int tid = threadIdx.x;
    for (int e = tid; e < 64 * 64; e += 256){
        int r = e >> 6, cc = e & 63;
        tl[r][cc] = W3[(size_t)(c0 + r) * Nn + n0 + cc];
    }
    __syncthreads();
    for (int e = tid; e < 64 * 64; e += 256){
        int rn = e >> 6, cc = e & 63;
        W3T[(size_t)(n0 + rn) * Cn + c0 + cc] = tl[cc][rn];
    }
}

// ---------------- k_fused: block0 = closed-form WTA; blocks 1.. = W1/W2 bulk ----------------
#define NB_W1 1024
#define NB_W2 1024

__global__ __launch_bounds__(512, 1) void k_fused(
        const float* __restrict__ M, const float4* __restrict__ cand,
        const float* __restrict__ thr1,
        const float* __restrict__ W1, const float* __restrict__ W2,
        float* __restrict__ o_W1, float* __restrict__ o_W2,
        float* __restrict__ r1pre, float* __restrict__ o_r1,
        int* __restrict__ j1s){
    __shared__ float4 s_mst[Hn];   // (off, ts, thb, 0) — 128 KB
    const int bid = blockIdx.x;
    const int tid = threadIdx.x;

    if (bid >= 1 && bid < 1 + NB_W1){
        size_t base = (size_t)(bid - 1) * 8192;
        const float4* src = (const float4*)W1;
        float4* dst = (float4*)o_W1;
        for (int i = tid; i < 8192; i += 512){
            float4 s = src[base + i];
            s.x = __fadd_rn(s.x, 0.01f); s.y = __fadd_rn(s.y, 0.01f);
            s.z = __fadd_rn(s.z, 0.01f); s.w = __fadd_rn(s.w, 0.01f);
            dst[base + i] = s;
        }
        return;
    }
    if (bid >= 1 + NB_W1){
        size_t base = (size_t)(bid - 1 - NB_W1) * 8192;
        const float4* src = (const float4*)W2;
        float4* dst = (float4*)o_W2;
        for (int i = tid; i < 8192; i += 512){
            float4 s = src[base + i];
            s.x = clamp01(s.x); s.y = clamp01(s.y);
            s.z = clamp01(s.z); s.w = clamp01(s.w);
            dst[base + i] = s;
        }
        return;
    }

    // ---- block 0: init state table, then single-wave WTA ----
    for (int h = tid; h < Hn; h += 512)
        s_mst[h] = make_float4(0.f, -1.f, thr1[h], 0.f);
    __syncthreads();
    if (tid >= 64) return;
    const int lane = tid;
    const float Lc = -0.15200309344504997f;   // log2(0.9)

    float4 cA0 = cand[lane],         cA1 = cand[64 + lane],         cA2 = cand[128 + lane];
    float4 cB0 = cand[CAP + lane],   cB1 = cand[CAP + 64 + lane],   cB2 = cand[CAP + 128 + lane];
    float4 cC0 = cand[2*CAP + lane], cC1 = cand[2*CAP + 64 + lane], cC2 = cand[2*CAP + 128 + lane];
    float4 gA0 = s_mst[__float_as_int(cA0.y) & 8191];
    float4 gA1 = s_mst[__float_as_int(cA1.y) & 8191];
    float4 gA2 = s_mst[__float_as_int(cA2.y) & 8191];

    for (int t = 0; t < Tt; ++t){
        const float tf = (float)t;
        // [1] closed-form mems + local best (payload: raw M, ts, thb)
        float bm = -3.4e38f; int bhh = 0x7FFFFFFF;
        float braw = 0.f, bts = 0.f, bthb = 0.f;
#define CPROC(c) { \
        int mc = __float_as_int(cA##c.y); \
        int hc = mc & 8191; \
        float dd = __fsub_rn(tf, gA##c.y); \
        float mem = __fsub_rn(cA##c.x, __fmul_rn(exp2f(__fmul_rn(dd, Lc)), gA##c.x)); \
        if (!((mc >> 15) & 1)) mem = -3.4e38f; \
        if (mem > bm || (mem == bm && hc < bhh)){ bm = mem; bhh = hc; braw = cA##c.x; bts = gA##c.y; bthb = gA##c.z; } }
        CPROC(0) CPROC(1) CPROC(2)
#undef CPROC
        // [2] speculative gathers for next step's candidates (patched on fire)
        const int hB0 = __float_as_int(cB0.y) & 8191;
        const int hB1 = __float_as_int(cB1.y) & 8191;
        const int hB2 = __float_as_int(cB2.y) & 8191;
        float4 gB0 = s_mst[hB0];
        float4 gB1 = s_mst[hB1];
        float4 gB2 = s_mst[hB2];
        // [3] argmax + payload broadcast
        float wv; int wh;
        int wl = wave_argmax_l(bm, bhh, wv, wh);
        float raw = rl_f(braw, wl), tsv = rl_f(bts, wl), thb = rl_f(bthb, wl);
        // [4] guards: winner-in-list theorem (mem <= M for all; unlisted M < vcap)
        const float vc = cA0.w;
        int skip = 0;
        if (wv < vc){
            if (t > 0 && vc < 150.f){
                skip = 1;   // every neuron's mem < vc < min threshold: no fire anywhere
            } else {
                // exact fallback: full scan (never taken in practice)
                float fv = -3.4e38f; int fh = 0x7FFFFFFF;
                float fraw = 0.f, fts = 0.f, fthb = 0.f;
                const float4* Mrow4 = (const float4*)(M + (size_t)t * Hn);
                for (int q = 0; q < 32; ++q){
                    int e = q * 64 + lane;
                    float4 mv = Mrow4[e];
                    int ib = e * 4;
                    float4 g0 = s_mst[ib+0], g1 = s_mst[ib+1], g2 = s_mst[ib+2], g3 = s_mst[ib+3];
#define FPROC(comp, gg, o2) { float x = mv.comp; float dd = __fsub_rn(tf, gg.y); \
                    float mm = __fsub_rn(x, __fmul_rn(exp2f(__fmul_rn(dd, Lc)), gg.x)); \
                    int h2 = ib + o2; \
                    if (mm > fv || (mm == fv && h2 < fh)){ fv = mm; fh = h2; fraw = x; fts = gg.y; fthb = gg.z; } }
                    FPROC(x, g0, 0) FPROC(y, g1, 1) FPROC(z, g2, 2) FPROC(w, g3, 3)
#undef FPROC
                }
                wl = wave_argmax_l(fv, fh, wv, wh);
                raw = rl_f(fraw, wl); tsv = rl_f(fts, wl); thb = rl_f(fthb, wl);
            }
        }
        // [5] unified fire decision (never-fired: ts=-1, thb=thr1 -> nup=t)
        int fire = 0; float thnew = 0.f;
        if (!skip){
            float te = th_lazy2(thb, 150.f, 400.f, t - (int)tsv - 1);
            if (wv > te){
                fire = 1;
                thnew = fminf(fmaxf(__fadd_rn(__fsub_rn(te, 0.05f), 5.0f), 150.f), 400.f);
            }
        }
        if (fire){
            if (lane == 0){
                j1s[t] = wh;
                if (tsv < 0.f){ o_r1[wh] = tf + 1.f; r1pre[wh] = tf + 1.f; }
                s_mst[wh] = make_float4(raw, tf, thnew, 0.f);
            }
            float4 upd = make_float4(raw, tf, thnew, 0.f);
            if (hB0 == wh) gB0 = upd;
            if (hB1 == wh) gB1 = upd;
            if (hB2 == wh) gB2 = upd;
        } else {
            if (lane == 0) j1s[t] = -1;
        }
        // [6] rotate
        cA0 = cB0; cA1 = cB1; cA2 = cB2;
        cB0 = cC0; cB1 = cC1; cB2 = cC2;
        int tn = (t + 3 < Tt) ? t + 3 : Tt - 1;
        cC0 = cand[(size_t)tn * CAP + lane];
        cC1 = cand[(size_t)tn * CAP + 64 + lane];
        cC2 = cand[(size_t)tn * CAP + 128 + lane];
        gA0 = gB0; gA1 = gB1; gA2 = gB2;
    }
}

// ---------------- k_postmap: j1s(h) -> j1slot(slot) + mh + nRout ----------------
__global__ __launch_bounds__(256) void k_postmap(const int* __restrict__ j1s,
        int* __restrict__ j1slot, int* __restrict__ mh, int* __restrict__ nRout){
    __shared__ unsigned bm[256];
    __shared__ int s_j[Tt];
    __shared__ int pre[257];
    int tid = threadIdx.x;
    bm[tid] = 0u;
    s_j[tid] = j1s[tid];
    __syncthreads();
    int h = s_j[tid];
    if (h >= 0) atomicOr(&bm[h >> 5], 1u << (h & 31));
    __syncthreads();
    pre[tid + 1] = __popc(bm[tid]);
    if (tid == 0) pre[0] = 0;
    __syncthreads();
    for (int off = 1; off < 256; off <<= 1){
        int v = (tid + 1 > off) ? pre[tid + 1 - off] : 0;
        __syncthreads();
        pre[tid + 1] += v;
        __syncthreads();
    }
    {
        unsigned w = bm[tid]; int base = pre[tid];
        while (w){ int b = __ffs(w) - 1; w &= w - 1; mh[base++] = (tid << 5) | b; }
    }
    {
        int hh = s_j[tid];
        if (hh >= 0){
            int word = hh >> 5, bit = hh & 31;
            j1slot[tid] = pre[word] + __popc(bm[word] & ((1u << bit) - 1u));
        } else j1slot[tid] = -1;
    }
    if (tid == 0) *nRout = pre[256];
}

// ---------------- k_colg ----------------
__global__ __launch_bounds__(256) void k_colg(const float* __restrict__ W2,
        const int* __restrict__ mh, const int* __restrict__ nRout,
        float* __restrict__ colv){
    int slot = blockIdx.x;
    if (slot >= *nRout) return;
    int h = mh[slot];
    int tid = threadIdx.x;
    float* dst = colv + (size_t)slot * Nn;
    for (int n = tid; n < Nn; n += 256) dst[n] = W2[(size_t)n * Hn + h];
}

// ---------------- k_lif2 ----------------
__global__ __launch_bounds__(64) void k_lif2(const float* __restrict__ colv,
        const int* __restrict__ j1slot, const float* __restrict__ thr2,
        float* __restrict__ o_r2, ull* __restrict__ spkb, unsigned* __restrict__ anyv){
    __shared__ int s_j[Tt];
    int lane = threadIdx.x, blk = blockIdx.x;
    for (int i = lane; i < Tt; i += 64) s_j[i] = j1slot[i];
    __syncthreads();
    int n = blk * 64 + lane;
    float tv = thr2[n], m = 0.f, rp = 0.f;
    for (int t = 0; t < Tt; ++t){
        int s = s_j[t];
        float u = (s >= 0) ? colv[(size_t)s * Nn + n] : 0.f;
        m = __fadd_rn(__fmul_rn(0.8f, m), u);
        int f = 0;
        if (m > tv){
            m = __fsub_rn(m, tv);
            if (rp == 0.f) rp = (float)(t + 1);
            f = 1;
        }
        ull mask = __ballot(f);
        if (lane == 0){
            spkb[t * 64 + blk] = mask;
            if (mask) atomicOr(&anyv[t], 1u);
        }
    }
    o_r2[n] = (rp == 0.f) ? 256.f : rp;
}

// ---------------- k_sim3 ----------------
__global__ __launch_bounds__(128, 1) void k_sim3(const ull* __restrict__ spkb,
        const unsigned* __restrict__ anyv, const float* __restrict__ W3T,
        const float* __restrict__ thr3, float* __restrict__ o_r3){
    int tid = threadIdx.x, lane = tid & 63, w = tid >> 6;
    __shared__ unsigned s_any[Tt];
    __shared__ ull s_r2[2];
    __shared__ int s_fire;
    for (int i = tid; i < Tt; i += 128) s_any[i] = anyv[i];
    float m = 0.f, th0 = thr3[tid], rp = 0.f, thv = 0.f;
    int ts = -1, zero = 1;
    __syncthreads();
    for (int t = 0; t < Tt; ++t){
        if (zero && s_any[t] == 0u) continue;
        float d = 0.f;
        if (s_any[t]){
            for (int ww = 0; ww < 64; ++ww){
                ull bits = spkb[t * 64 + ww];
                while (bits){
                    int b2 = __ffsll((long long)bits) - 1;
                    bits &= bits - 1;
                    d = __fadd_rn(d, W3T[(size_t)(ww * 64 + b2) * Cn + tid]);
                }
            }
        }
        m = __fadd_rn(__fmul_rn(0.9f, m), d);
        ull k = (((ull)__float_as_uint(m >= 0.f ? m : 0.f)) << 32) | (unsigned)(8191 - tid);
        if (!(m >= 0.f)) k = (unsigned)(8191 - tid);
#pragma unroll
        for (int off = 32; off >= 1; off >>= 1){
            ull o = __shfl_down(k, off);
            if (o > k) k = o;
        }
        if (lane == 0) s_r2[w] = k;
        __syncthreads();
        ull wk = s_r2[0] > s_r2[1] ? s_r2[0] : s_r2[1];
        int wc = 8191 - (int)(wk & 0xFFFFu);
        float wv = __uint_as_float((unsigned)(wk >> 32));
        if (tid == wc){
            float te = (ts < 0) ? th_lazy2(th0, 50.f, 200.f, t)
                                : th_lazy2(thv, 50.f, 200.f, t - ts - 1);
            int f = (wv > te) ? 1 : 0;
            s_fire = f;
            if (f){
                thv = fminf(fmaxf(__fadd_rn(__fsub_rn(te, 0.05f), 5.0f), 50.f), 200.f);
                ts = t;
                if (rp == 0.f) rp = (float)(t + 1);
            }
        }
        __syncthreads();
        if (s_fire){ m = 0.f; zero = 1; }
        else zero = 0;
        __syncthreads();
    }
    o_r3[tid] = (rp == 0.f) ? 256.f : rp;
}

// ---------------- k_scalars ----------------
__global__ __launch_bounds__(1024) void k_scalars(const float* __restrict__ image,
        const float* __restrict__ r1pre, const float* __restrict__ o_r1,
        const float* __restrict__ o_r2,
        float* __restrict__ zeta, float* __restrict__ rho,
        float* __restrict__ imgt, float* __restrict__ eiP, float* __restrict__ eiM,
        float* __restrict__ Pv, float* __restrict__ Qv,
        float* __restrict__ E2P, float* __restrict__ E2M,
        float* __restrict__ o_err, float* __restrict__ o_es){
    int tid = threadIdx.x;
    for (int h = tid; h < Hn; h += 1024){
        float r1f = o_r1[h];
        float mask = (r1pre[h] != 0.f) ? 1.f : 0.f;
        float z = __fmul_rn(__fmul_rn(__fsub_rn(256.f, r1f), mask), 0.00390625f);
        zeta[h] = z;
        Pv[h] = __expf(r1f * 0.05f) * z;
        Qv[h] = __expf(-r1f * 0.05f) * z;
    }
    float acc = 0.f;
    for (int n = tid; n < Nn; n += 1024){
        float img = __fmul_rn(256.f, image[n]);
        float r2f = o_r2[n];
        float e = __fmul_rn(__fsub_rn(img, __fsub_rn(r2f, 4.0f)), 0.00390625f);
        o_err[n] = e;
        rho[n] = __fadd_rn(__fmul_rn(__fsub_rn(__fsub_rn(r2f, 4.0f), img), 0.00390625f), 0.15f);
        imgt[n] = img;
        eiP[n] = __expf(img * 0.05f);
        eiM[n] = __expf(-img * 0.05f);
        E2P[n] = __expf(r2f * 0.05f);
        E2M[n] = __expf(-r2f * 0.05f);
        acc = __fadd_rn(acc, __fmul_rn(e, e));
    }
    __shared__ float red[16];
    for (int off = 32; off >= 1; off >>= 1) acc += __shfl_down(acc, off);
    int lane = tid & 63, w = tid >> 6;
    if (lane == 0) red[w] = acc;
    __syncthreads();
    if (tid == 0){
        float s = 0.f;
        for (int q = 0; q < 16; ++q) s += red[q];
        *o_es = s;
    }
}

// ---------------- k_w1fix ----------------
__global__ __launch_bounds__(256) void k_w1fix(const float* __restrict__ W1,
        const float* __restrict__ imgt, const float* __restrict__ eiP,
        const float* __restrict__ eiM, const float* __restrict__ o_r1,
        const int* __restrict__ mh, const int* __restrict__ nRout,
        float* __restrict__ o_W1){
    int slot = blockIdx.x;
    if (slot >= *nRout) return;
    int h = mh[slot];
    int tid = threadIdx.x;
    float r1f = o_r1[h];
    float a = 0.01f * __expf(-r1f * 0.05f);
    float b = 0.01f * __expf( r1f * 0.05f);
    const float4* src = (const float4*)(W1 + (size_t)h * Nn);
    float4* dst = (float4*)(o_W1 + (size_t)h * Nn);
    const float4* ig = (const float4*)imgt;
    const float4* p4 = (const float4*)eiP;
    const float4* m4 = (const float4*)eiM;
    for (int i = tid; i < Nn / 4; i += 256){
        float4 s = src[i];
        float4 im = ig[i], pp = p4[i], mm = m4[i];
        s.x += (r1f >= im.x) ? a * pp.x : -(b * mm.x);
        s.y += (r1f >= im.y) ? a * pp.y : -(b * mm.y);
        s.z += (r1f >= im.z) ? a * pp.z : -(b * mm.z);
        s.w += (r1f >= im.w) ? a * pp.w : -(b * mm.w);
        dst[i] = s;
    }
}

// ---------------- k_w2fix ----------------
__global__ __launch_bounds__(128) void k_w2fix(
        const float* __restrict__ o_r1, const float* __restrict__ Pv,
        const float* __restrict__ Qv, const float* __restrict__ o_r2,
        const float* __restrict__ rho, const int* __restrict__ mh,
        const int* __restrict__ nRout, float* __restrict__ o_W2){
    __shared__ int   s_h[Tt];
    __shared__ float s_rv[Tt], s_pp[Tt], s_qq[Tt];
    int n = blockIdx.x, tid = threadIdx.x;
    int nRv = *nRout;
    for (int s = tid; s < nRv; s += 128){
        int h = mh[s];
        s_h[s] = h; s_rv[s] = o_r1[h]; s_pp[s] = Pv[h]; s_qq[s] = Qv[h];
    }
    __syncthreads();
    float r2f = o_r2[n], rh = rho[n];
    float A = 0.01f * rh * __expf(-r2f * 0.05f);
    float B = 0.01f * rh * __expf( r2f * 0.05f);
    for (int s = tid; s < nRv; s += 128){
        size_t idx = (size_t)n * Hn + s_h[s];
        float w = o_W2[idx];
        float rv = s_rv[s];
        w = clamp01(w + ((r2f >= rv) ? A * s_pp[s] : -(B * s_qq[s])));
        o_W2[idx] = w;
    }
}

// ---------------- k_w3new ----------------
__global__ __launch_bounds__(256) void k_w3new(const float* __restrict__ W3,
        const float* __restrict__ o_r2, const float* __restrict__ E2P,
        const float* __restrict__ E2M, const float* __restrict__ o_r3,
        float* __restrict__ o_W3){
    int c = blockIdx.x, tid = threadIdx.x;
    float r3f = o_r3[c];
    float a = 0.01f * __expf(-r3f * 0.05f);
    float b = 0.01f * __expf( r3f * 0.05f);
    const float4* src = (const float4*)(W3 + (size_t)c * Nn);
    float4* dst = (float4*)(o_W3 + (size_t)c * Nn);
    const float4* r24 = (const float4*)o_r2;
    const float4* p4 = (const float4*)E2P;
    const float4* m4 = (const float4*)E2M;
    for (int i = tid; i < Nn / 4; i += 256){
        float4 s = src[i]; float4 rv = r24[i]; float4 pp = p4[i]; float4 mm = m4[i];
        s.x += (r3f >= rv.x) ? a * pp.x : -(b * mm.x);
        s.y += (r3f >= rv.y) ? a * pp.y : -(b * mm.y);
        s.z += (r3f >= rv.z) ? a * pp.z : -(b * mm.z);
        s.w += (r3f >= rv.w) ? a * pp.w : -(b * mm.w);
        dst[i] = s;
    }
}

extern "C" void kernel_launch(void* const* d_in, const int* in_sizes, int n_in,
                              void* d_out, int out_size, void* d_ws, size_t ws_size,
                              hipStream_t stream){
    const float* image = (const float*)d_in[0];
    const float* W1   = (const float*)d_in[1];
    const float* W2   = (const float*)d_in[2];
    const float* W3   = (const float*)d_in[3];
    const float* thr1 = (const float*)d_in[4];
    const float* thr2 = (const float*)d_in[5];
    const float* thr3 = (const float*)d_in[6];

    float* out  = (float*)d_out;
    float* o_err = out;
    float* o_es  = out + 4096;
    float* o_r1  = out + 4097;
    float* o_r2  = out + 12289;
    float* o_r3  = out + 16385;
    float* o_W1  = out + 16513;
    float* o_W2  = o_W1 + (size_t)Hn * Nn;
    float* o_W3  = o_W2 + (size_t)Nn * Hn;

    float* ws = (float*)d_ws;
    float* G_T   = ws;                                  // H*T
    float* M     = G_T + (size_t)Hn * Tt;               // T*H
    float* W3T   = M + (size_t)Tt * Hn;                 // N*C
    float* colv  = W3T + (size_t)Nn * Cn;               // 256*N
    float4* cand = (float4*)(colv + (size_t)256 * Nn);  // T*CAP float4
    ull* spkb    = (ull*)(cand + (size_t)Tt * CAP);     // T*64
    float* r1pre = (float*)(spkb + (size_t)Tt * 64);    // H
    float* zeta  = r1pre + Hn;                          // H
    float* rho   = zeta + Hn;                           // N
    float* imgt  = rho + Nn;                            // N
    float* eiP   = imgt + Nn;                           // N
    float* eiM   = eiP + Nn;                            // N
    float* Pv    = eiM + Nn;                            // H
    float* Qv    = Pv + Hn;                             // H
    float* E2P   = Qv + Hn;                             // N
    float* E2M   = E2P + Nn;                            // N
    int* boff   = (int*)(E2M + Nn);                     // T+1
    int* sidx   = boff + (Tt + 1);                      // N
    int* j1s    = sidx + Nn;                            // T (h-indices)
    int* j1slot = j1s + Tt;                             // T
    int* mh     = j1slot + Tt;                          // 256
    int* nRout  = mh + 256;                             // 1
    unsigned* anyv = (unsigned*)(nRout + 1);            // T

    k_prep<<<1, 1024, 0, stream>>>(image, boff, sidx, anyv);
    k_gbuckets<<<Hn / 4, 256, 0, stream>>>(W1, boff, sidx, G_T);
    k_c1M<<<Hn / 32, 256, 0, stream>>>(G_T, M, r1pre, o_r1);
    k_sel<<<Tt, 256, 0, stream>>>(M, cand);
    k_w3t<<<128, 256, 0, stream>>>(W3, W3T);
    k_fused<<<1 + NB_W1 + NB_W2, 512, 0, stream>>>(
        M, cand, thr1, W1, W2, o_W1, o_W2, r1pre, o_r1, j1s);
    k_postmap<<<1, 256, 0, stream>>>(j1s, j1slot, mh, nRout);
    k_colg<<<256, 256, 0, stream>>>(W2, mh, nRout, colv);
    k_lif2<<<Nn / 64, 64, 0, stream>>>(colv, j1slot, thr2, o_r2, spkb, anyv);
    k_sim3<<<1, 128, 0, stream>>>(spkb, anyv, W3T, thr3, o_r3);
    k_scalars<<<1, 1024, 0, stream>>>(image, r1pre, o_r1, o_r2, zeta, rho,
                                      imgt, eiP, eiM, Pv, Qv, E2P, E2M, o_err, o_es);
    k_w1fix<<<256, 256, 0, stream>>>(W1, imgt, eiP, eiM, o_r1, mh, nRout, o_W1);
    k_w2fix<<<Nn, 128, 0, stream>>>(o_r1, Pv, Qv, o_r2, rho, mh, nRout, o_W2);
    k_w3new<<<Cn, 256, 0, stream>>>(W3, o_r2, E2P, E2M, o_r3, o_W3);
}

// Round 11
// 563.471 us; speedup vs baseline: 1.4929x; 1.0066x over previous
//
#include <hip/hip_runtime.h>
#include <cstdint>
#include <cstddef>

#define Hn 8192
#define Nn 4096
#define Cn 128
#define Tt 256
#define CAP 192

typedef unsigned long long ull;

// th after nup clip-updates (decay -0.05 each) from base b, clamped [lo,hi]
__device__ __forceinline__ float th_lazy2(float b, float lo, float hi, int nup){
    if (nup <= 0) return b;
    float a = fminf(fmaxf(__fsub_rn(b, 0.05f), lo), hi);
    if (nup == 1) return a;
    return fmaxf(__fsub_rn(a, __fmul_rn(0.05f, (float)(nup - 1))), lo);
}

__device__ __forceinline__ float clamp01(float v){
    return fminf(fmaxf(v, 0.f), 1.f);
}

// ---- DPP cross-lane reduce (VALU pipe) ----
template<int CTRL>
__device__ __forceinline__ int dpp_i(int x, int old){
    return __builtin_amdgcn_update_dpp(old, x, CTRL, 0xf, 0xf, false);
}
__device__ __forceinline__ float wave_max_f(float v){
    const int NEG = __float_as_int(-3.4e38f);
#define STEPM(C) { float o = __int_as_float(dpp_i<C>(__float_as_int(v), NEG)); v = fmaxf(v, o); }
    STEPM(0x111) STEPM(0x112) STEPM(0x114) STEPM(0x118) STEPM(0x142) STEPM(0x143)
#undef STEPM
    return __int_as_float(__builtin_amdgcn_readlane(__float_as_int(v), 63));
}
// argmax (value desc, index asc); returns winner lane, sets wv/wh.
__device__ __forceinline__ int wave_argmax_l(float bv, int bh, float &wv, int &wh){
    float v = wave_max_f(bv);
    ull tie = __ballot(bv == v);
    int tl = __ffsll((long long)tie) - 1;
    int h = __builtin_amdgcn_readlane(bh, tl);
    if (__builtin_expect(__popcll(tie) > 1, 0)){
        ull m = tie & (tie - 1);
        while (m){
            int l2 = __ffsll((long long)m) - 1;
            int h2 = __builtin_amdgcn_readlane(bh, l2);
            if (h2 < h){ h = h2; tl = l2; }
            m &= m - 1;
        }
    }
    wv = v; wh = h; return tl;
}
__device__ __forceinline__ float rl_f(float x, int l){
    return __int_as_float(__builtin_amdgcn_readlane(__float_as_int(x), l));
}

// ---------------- k_prep ----------------
__global__ __launch_bounds__(1024) void k_prep(const float* __restrict__ image,
        int* __restrict__ boff, int* __restrict__ sidx, unsigned* __restrict__ anyv){
    __shared__ int s_start[Nn];
    __shared__ int s_c4[4][Tt];
    __shared__ int s_boff[Tt + 1];
    int tid = threadIdx.x;
    for (int i = tid; i < Nn; i += 1024)
        s_start[i] = (int)floorf(__fmul_rn(256.f, image[i]));
    if (tid < Tt) anyv[tid] = 0u;
    __syncthreads();
    int b = tid & 255, q = tid >> 8;
    {
        int c = 0;
        for (int k = 0; k < 1024; ++k) c += (s_start[q * 1024 + k] == b) ? 1 : 0;
        s_c4[q][b] = c;
    }
    __syncthreads();
    if (tid == 0){
        int acc = 0;
        for (int bb = 0; bb < Tt; ++bb){
            s_boff[bb] = acc;
            acc += s_c4[0][bb] + s_c4[1][bb] + s_c4[2][bb] + s_c4[3][bb];
        }
        s_boff[Tt] = acc;
    }
    __syncthreads();
    if (tid <= Tt) boff[tid] = s_boff[tid];
    int p = s_boff[b];
    if (q > 0) p += s_c4[0][b];
    if (q > 1) p += s_c4[1][b];
    if (q > 2) p += s_c4[2][b];
    for (int k = 0; k < 1024; ++k){
        int i = q * 1024 + k;
        if (s_start[i] == b) sidx[p++] = i;
    }
}

// ---------------- k_gbuckets: 2 rows/block, 32 KB LDS (20 waves/CU) ----------------
__global__ __launch_bounds__(256) void k_gbuckets(const float* __restrict__ W1,
        const int* __restrict__ boff, const int* __restrict__ sidx,
        float* __restrict__ G_T){
    __shared__ float rows[2][Nn];   // 32 KB
    int tid = threadIdx.x;
    int h0 = blockIdx.x * 2;
    for (int r = 0; r < 2; ++r){
        const float4* src = (const float4*)(W1 + (size_t)(h0 + r) * Nn);
        float4* dst = (float4*)rows[r];
        for (int j = tid; j < Nn / 4; j += 256) dst[j] = src[j];
    }
    __syncthreads();
    int t = tid;
    int b0 = boff[t], b1 = boff[t + 1];
    float s0 = 0.f, s1 = 0.f;
    for (int k = b0; k < b1; ++k){
        int i = sidx[k];
        s0 += rows[0][i]; s1 += rows[1][i];
    }
    G_T[(size_t)(h0 + 0) * Tt + t] = s0;
    G_T[(size_t)(h0 + 1) * Tt + t] = s1;
}

// ---------------- k_c1M: window-sum + M-scan + r1 init ----------------
__global__ __launch_bounds__(256) void k_c1M(const float* __restrict__ G_T,
        float* __restrict__ M, float* __restrict__ r1pre, float* __restrict__ o_r1){
    __shared__ float tile[32][Tt + 1];
    __shared__ float c1s[32][Tt + 1];
    const int tid = threadIdx.x;
    const int h0 = blockIdx.x * 32;
    for (int r = 0; r < 32; ++r) tile[r][tid] = G_T[(size_t)(h0 + r) * Tt + tid];
    __syncthreads();
    {
        int hs = tid & 31, ts = tid >> 5;
        for (int tb = 0; tb < 32; ++tb){
            int t = tb * 8 + ts;
            int lo = (t - 7 < 0) ? 0 : t - 7;
            float s = 0.f;
            for (int u = lo; u <= t; ++u) s += tile[hs][u];
            c1s[hs][t] = s;
        }
    }
    __syncthreads();
    if (tid < 32){
        float m = 0.f;
        for (int t = 0; t < Tt; ++t){
            m = __fadd_rn(__fmul_rn(0.9f, m), c1s[tid][t]);
            M[(size_t)t * Hn + h0 + tid] = m;
        }
        r1pre[h0 + tid] = 0.f;
        o_r1[h0 + tid] = 256.f;
    }
}

// ---------------- k_sel: rank-CAP radix select; cand = (val, idx|valid<<15, 0, vcap) ----------------
__global__ __launch_bounds__(256) void k_sel(const float* __restrict__ M,
        float4* __restrict__ cand){
    const int t = blockIdx.x, tid = threadIdx.x;
    __shared__ float s_row[Hn];
    __shared__ unsigned s_hist[256];
    __shared__ unsigned s_suf[256];
    __shared__ unsigned s_pref;
    __shared__ int s_rank;
    __shared__ int s_cnt;
    __shared__ int s_idx[CAP + 64];
    {
        const float4* src = (const float4*)(M + (size_t)t * Hn);
        float4* d4 = (float4*)s_row;
        for (int j = tid; j < Hn / 4; j += 256) d4[j] = src[j];
    }
    if (tid == 0){ s_pref = 0u; s_rank = CAP; s_cnt = 0; }
    __syncthreads();
#pragma unroll
    for (int b = 3; b >= 0; --b){
        s_hist[tid] = 0u;
        __syncthreads();
        unsigned pref = s_pref;
        int r = s_rank;
        for (int k = 0; k < 32; ++k){
            unsigned u = __float_as_uint(s_row[tid + (k << 8)]);
            bool match = (b == 3) ? true : ((u >> ((b + 1) * 8)) == pref);
            if (match) atomicAdd(&s_hist[(u >> (b * 8)) & 255], 1u);
        }
        __syncthreads();
        s_suf[tid] = s_hist[tid];
        __syncthreads();
#pragma unroll
        for (int off = 1; off < 256; off <<= 1){
            unsigned v = (tid + off < 256) ? s_suf[tid + off] : 0u;
            __syncthreads();
            s_suf[tid] += v;
            __syncthreads();
        }
        unsigned above = s_suf[tid] - s_hist[tid];
        if ((int)above < r && r <= (int)s_suf[tid]){
            s_pref = (pref << 8) | (unsigned)tid;
            s_rank = r - (int)above;
        }
        __syncthreads();
    }
    unsigned V = s_pref;
    for (int k = 0; k < 32; ++k){
        int i = tid + (k << 8);
        unsigned u = __float_as_uint(s_row[i]);
        if (u >= V){
            int p = atomicAdd(&s_cnt, 1);
            if (p < CAP + 64) s_idx[p] = i;
        }
    }
    __syncthreads();
    int c = s_cnt;
    bool ovf = (c > CAP);
    float vV = ovf ? 3.4e38f : __uint_as_float(V);
    for (int i = tid; i < CAP; i += 256){
        float4 e;
        if (!ovf && i < c){
            int ix = s_idx[i];
            e = make_float4(s_row[ix], __int_as_float(ix | (1 << 15)), 0.f, vV);
        } else {
            e = make_float4(-1.f, 0.f, 0.f, vV);
        }
        cand[(size_t)t * CAP + i] = e;
    }
}

// ---------------- k_w3t ----------------
__global__ __launch_bounds__(256) void k_w3t(const float* __restrict__ W3,
                                             float* __restrict__ W3T){
    __shared__ float tl[64][65];
    int bx = blockIdx.x & 63, by = blockIdx.x >> 6;
    int n0 = bx * 64, c0 = by * 64;
    int tid = threadIdx.x;
    for (int e = tid; e < 64 * 64; e += 256){
        int r = e >> 6, cc = e & 63;
        tl[r][cc] = W3[(size_t)(c0 + r) * Nn + n0 + cc];
    }
    __syncthreads();
    for (int e = tid; e < 64 * 64; e += 256){
        int rn = e >> 6, cc = e & 63;
        W3T[(size_t)(n0 + rn) * Cn + c0 + cc] = tl[cc][rn];
    }
}

// ---------------- k_fused: block0 = closed-form WTA (72 KB SoA state); blocks 1.. = W1/W2 bulk ----------------
#define NB_W1 1024
#define NB_W2 1024

__global__ __launch_bounds__(512, 4) void k_fused(
        const float* __restrict__ M, const float4* __restrict__ cand,
        const float* __restrict__ thr1,
        const float* __restrict__ W1, const float* __restrict__ W2,
        float* __restrict__ o_W1, float* __restrict__ o_W2,
        float* __restrict__ r1pre, float* __restrict__ o_r1,
        int* __restrict__ j1s){
    __shared__ float s_off[Hn];            // 32 KB
    __shared__ float s_thb[Hn];            // 32 KB
    __shared__ unsigned char s_ts[Hn];     // 8 KB   (enc: t_fire+1, 0 = never)
    const int bid = blockIdx.x;
    const int tid = threadIdx.x;

    if (bid >= 1 && bid < 1 + NB_W1){
        size_t base = (size_t)(bid - 1) * 8192;
        const float4* src = (const float4*)W1;
        float4* dst = (float4*)o_W1;
        for (int i = tid; i < 8192; i += 512){
            float4 s = src[base + i];
            s.x = __fadd_rn(s.x, 0.01f); s.y = __fadd_rn(s.y, 0.01f);
            s.z = __fadd_rn(s.z, 0.01f); s.w = __fadd_rn(s.w, 0.01f);
            dst[base + i] = s;
        }
        return;
    }
    if (bid >= 1 + NB_W1){
        size_t base = (size_t)(bid - 1 - NB_W1) * 8192;
        const float4* src = (const float4*)W2;
        float4* dst = (float4*)o_W2;
        for (int i = tid; i < 8192; i += 512){
            float4 s = src[base + i];
            s.x = clamp01(s.x); s.y = clamp01(s.y);
            s.z = clamp01(s.z); s.w = clamp01(s.w);
            dst[base + i] = s;
        }
        return;
    }

    // ---- block 0: init state table, then single-wave WTA ----
    for (int h = tid; h < Hn; h += 512){
        s_off[h] = 0.f;
        s_thb[h] = thr1[h];
        s_ts[h] = 0;
    }
    __syncthreads();
    if (tid >= 64) return;
    const int lane = tid;
    const float Lc = -0.15200309344504997f;   // log2(0.9)

    float4 cA0 = cand[lane],         cA1 = cand[64 + lane],         cA2 = cand[128 + lane];
    float4 cB0 = cand[CAP + lane],   cB1 = cand[CAP + 64 + lane],   cB2 = cand[CAP + 128 + lane];
    float4 cC0 = cand[2*CAP + lane], cC1 = cand[2*CAP + 64 + lane], cC2 = cand[2*CAP + 128 + lane];
    float4 gA0, gA1, gA2;
    {
        int h0 = __float_as_int(cA0.y) & 8191;
        int h1 = __float_as_int(cA1.y) & 8191;
        int h2 = __float_as_int(cA2.y) & 8191;
        gA0 = make_float4(s_off[h0], (float)s_ts[h0] - 1.f, s_thb[h0], 0.f);
        gA1 = make_float4(s_off[h1], (float)s_ts[h1] - 1.f, s_thb[h1], 0.f);
        gA2 = make_float4(s_off[h2], (float)s_ts[h2] - 1.f, s_thb[h2], 0.f);
    }

    for (int t = 0; t < Tt; ++t){
        const float tf = (float)t;
        // [1] closed-form mems + local best (payload: raw M, ts, thb)
        float bm = -3.4e38f; int bhh = 0x7FFFFFFF;
        float braw = 0.f, bts = 0.f, bthb = 0.f;
#define CPROC(c) { \
        int mc = __float_as_int(cA##c.y); \
        int hc = mc & 8191; \
        float dd = __fsub_rn(tf, gA##c.y); \
        float mem = __fsub_rn(cA##c.x, __fmul_rn(exp2f(__fmul_rn(dd, Lc)), gA##c.x)); \
        if (!((mc >> 15) & 1)) mem = -3.4e38f; \
        if (mem > bm || (mem == bm && hc < bhh)){ bm = mem; bhh = hc; braw = cA##c.x; bts = gA##c.y; bthb = gA##c.z; } }
        CPROC(0) CPROC(1) CPROC(2)
#undef CPROC
        // [2] speculative gathers for next step's candidates (patched on fire)
        const int hB0 = __float_as_int(cB0.y) & 8191;
        const int hB1 = __float_as_int(cB1.y) & 8191;
        const int hB2 = __float_as_int(cB2.y) & 8191;
        float4 gB0 = make_float4(s_off[hB0], (float)s_ts[hB0] - 1.f, s_thb[hB0], 0.f);
        float4 gB1 = make_float4(s_off[hB1], (float)s_ts[hB1] - 1.f, s_thb[hB1], 0.f);
        float4 gB2 = make_float4(s_off[hB2], (float)s_ts[hB2] - 1.f, s_thb[hB2], 0.f);
        // [3] argmax + payload broadcast
        float wv; int wh;
        int wl = wave_argmax_l(bm, bhh, wv, wh);
        float raw = rl_f(braw, wl), tsv = rl_f(bts, wl), thb = rl_f(bthb, wl);
        // [4] guards: winner-in-list theorem (mem <= M for all; unlisted M < vcap)
        const float vc = cA0.w;
        int skip = 0;
        if (wv < vc){
            if (t > 0 && vc < 150.f){
                skip = 1;   // every neuron's mem < vc < min threshold: no fire anywhere
            } else {
                // exact fallback: full scan (never taken in practice)
                float fv = -3.4e38f; int fh = 0x7FFFFFFF;
                float fraw = 0.f, fts = 0.f, fthb = 0.f;
                const float4* Mrow4 = (const float4*)(M + (size_t)t * Hn);
                for (int q = 0; q < 32; ++q){
                    int e = q * 64 + lane;
                    float4 mv = Mrow4[e];
                    int ib = e * 4;
#define FPROC(comp, o2) { float x = mv.comp; int h2 = ib + o2; \
                    float gts = (float)s_ts[h2] - 1.f; \
                    float dd = __fsub_rn(tf, gts); \
                    float mm = __fsub_rn(x, __fmul_rn(exp2f(__fmul_rn(dd, Lc)), s_off[h2])); \
                    if (mm > fv || (mm == fv && h2 < fh)){ fv = mm; fh = h2; fraw = x; fts = gts; fthb = s_thb[h2]; } }
                    FPROC(x, 0) FPROC(y, 1) FPROC(z, 2) FPROC(w, 3)
#undef FPROC
                }
                wl = wave_argmax_l(fv, fh, wv, wh);
                raw = rl_f(fraw, wl); tsv = rl_f(fts, wl); thb = rl_f(fthb, wl);
            }
        }
        // [5] unified fire decision (never-fired: ts=-1, thb=thr1 -> nup=t)
        int fire = 0; float thnew = 0.f;
        if (!skip){
            float te = th_lazy2(thb, 150.f, 400.f, t - (int)tsv - 1);
            if (wv > te){
                fire = 1;
                thnew = fminf(fmaxf(__fadd_rn(__fsub_rn(te, 0.05f), 5.0f), 150.f), 400.f);
            }
        }
        if (fire){
            if (lane == 0){
                j1s[t] = wh;
                if (tsv < 0.f){ o_r1[wh] = tf + 1.f; r1pre[wh] = tf + 1.f; }
                s_off[wh] = raw;
                s_ts[wh] = (unsigned char)((t + 1 < 256) ? (t + 1) : 255); // t=255 state never read
                s_thb[wh] = thnew;
            }
            float4 upd = make_float4(raw, tf, thnew, 0.f);
            if (hB0 == wh) gB0 = upd;
            if (hB1 == wh) gB1 = upd;
            if (hB2 == wh) gB2 = upd;
        } else {
            if (lane == 0) j1s[t] = -1;
        }
        // [6] rotate
        cA0 = cB0; cA1 = cB1; cA2 = cB2;
        cB0 = cC0; cB1 = cC1; cB2 = cC2;
        int tn = (t + 3 < Tt) ? t + 3 : Tt - 1;
        cC0 = cand[(size_t)tn * CAP + lane];
        cC1 = cand[(size_t)tn * CAP + 64 + lane];
        cC2 = cand[(size_t)tn * CAP + 128 + lane];
        gA0 = gB0; gA1 = gB1; gA2 = gB2;
    }
}

// ---------------- k_postmap: j1s(h) -> j1slot(slot) + mh + nRout ----------------
__global__ __launch_bounds__(256) void k_postmap(const int* __restrict__ j1s,
        int* __restrict__ j1slot, int* __restrict__ mh, int* __restrict__ nRout){
    __shared__ unsigned bm[256];
    __shared__ int s_j[Tt];
    __shared__ int pre[257];
    int tid = threadIdx.x;
    bm[tid] = 0u;
    s_j[tid] = j1s[tid];
    __syncthreads();
    int h = s_j[tid];
    if (h >= 0) atomicOr(&bm[h >> 5], 1u << (h & 31));
    __syncthreads();
    pre[tid + 1] = __popc(bm[tid]);
    if (tid == 0) pre[0] = 0;
    __syncthreads();
    for (int off = 1; off < 256; off <<= 1){
        int v = (tid + 1 > off) ? pre[tid + 1 - off] : 0;
        __syncthreads();
        pre[tid + 1] += v;
        __syncthreads();
    }
    {
        unsigned w = bm[tid]; int base = pre[tid];
        while (w){ int b = __ffs(w) - 1; w &= w - 1; mh[base++] = (tid << 5) | b; }
    }
    {
        int hh = s_j[tid];
        if (hh >= 0){
            int word = hh >> 5, bit = hh & 31;
            j1slot[tid] = pre[word] + __popc(bm[word] & ((1u << bit) - 1u));
        } else j1slot[tid] = -1;
    }
    if (tid == 0) *nRout = pre[256];
}

// ---------------- k_colg ----------------
__global__ __launch_bounds__(256) void k_colg(const float* __restrict__ W2,
        const int* __restrict__ mh, const int* __restrict__ nRout,
        float* __restrict__ colv){
    int slot = blockIdx.x;
    if (slot >= *nRout) return;
    int h = mh[slot];
    int tid = threadIdx.x;
    float* dst = colv + (size_t)slot * Nn;
    for (int n = tid; n < Nn; n += 256) dst[n] = W2[(size_t)n * Hn + h];
}

// ---------------- k_lif2: serial-t LIF with 1-step drive prefetch ----------------
__global__ __launch_bounds__(64) void k_lif2(const float* __restrict__ colv,
        const int* __restrict__ j1slot, const float* __restrict__ thr2,
        float* __restrict__ o_r2, ull* __restrict__ spkb, unsigned* __restrict__ anyv){
    __shared__ int s_j[Tt];
    int lane = threadIdx.x, blk = blockIdx.x;
    for (int i = lane; i < Tt; i += 64) s_j[i] = j1slot[i];
    __syncthreads();
    int n = blk * 64 + lane;
    float tv = thr2[n], m = 0.f, rp = 0.f;
    int s0v = s_j[0];
    float u0 = (s0v >= 0) ? colv[(size_t)s0v * Nn + n] : 0.f;
    for (int t = 0; t < Tt; ++t){
        // prefetch next step's drive (hides L2 latency under this step's work)
        float u1 = 0.f;
        if (t + 1 < Tt){
            int s1v = s_j[t + 1];
            if (s1v >= 0) u1 = colv[(size_t)s1v * Nn + n];
        }
        m = __fadd_rn(__fmul_rn(0.8f, m), u0);
        int f = 0;
        if (m > tv){
            m = __fsub_rn(m, tv);
            if (rp == 0.f) rp = (float)(t + 1);
            f = 1;
        }
        ull mask = __ballot(f);
        if (lane == 0){
            spkb[t * 64 + blk] = mask;
            if (mask) atomicOr(&anyv[t], 1u);
        }
        u0 = u1;
    }
    o_r2[n] = (rp == 0.f) ? 256.f : rp;
}

// ---------------- k_sim3 ----------------
__global__ __launch_bounds__(128, 1) void k_sim3(const ull* __restrict__ spkb,
        const unsigned* __restrict__ anyv, const float* __restrict__ W3T,
        const float* __restrict__ thr3, float* __restrict__ o_r3){
    int tid = threadIdx.x, lane = tid & 63, w = tid >> 6;
    __shared__ unsigned s_any[Tt];
    __shared__ ull s_r2[2];
    __shared__ int s_fire;
    for (int i = tid; i < Tt; i += 128) s_any[i] = anyv[i];
    float m = 0.f, th0 = thr3[tid], rp = 0.f, thv = 0.f;
    int ts = -1, zero = 1;
    __syncthreads();
    for (int t = 0; t < Tt; ++t){
        if (zero && s_any[t] == 0u) continue;
        float d = 0.f;
        if (s_any[t]){
            for (int ww = 0; ww < 64; ++ww){
                ull bits = spkb[t * 64 + ww];
                while (bits){
                    int b2 = __ffsll((long long)bits) - 1;
                    bits &= bits - 1;
                    d = __fadd_rn(d, W3T[(size_t)(ww * 64 + b2) * Cn + tid]);
                }
            }
        }
        m = __fadd_rn(__fmul_rn(0.9f, m), d);
        ull k = (((ull)__float_as_uint(m >= 0.f ? m : 0.f)) << 32) | (unsigned)(8191 - tid);
        if (!(m >= 0.f)) k = (unsigned)(8191 - tid);
#pragma unroll
        for (int off = 32; off >= 1; off >>= 1){
            ull o = __shfl_down(k, off);
            if (o > k) k = o;
        }
        if (lane == 0) s_r2[w] = k;
        __syncthreads();
        ull wk = s_r2[0] > s_r2[1] ? s_r2[0] : s_r2[1];
        int wc = 8191 - (int)(wk & 0xFFFFu);
        float wv = __uint_as_float((unsigned)(wk >> 32));
        if (tid == wc){
            float te = (ts < 0) ? th_lazy2(th0, 50.f, 200.f, t)
                                : th_lazy2(thv, 50.f, 200.f, t - ts - 1);
            int f = (wv > te) ? 1 : 0;
            s_fire = f;
            if (f){
                thv = fminf(fmaxf(__fadd_rn(__fsub_rn(te, 0.05f), 5.0f), 50.f), 200.f);
                ts = t;
                if (rp == 0.f) rp = (float)(t + 1);
            }
        }
        __syncthreads();
        if (s_fire){ m = 0.f; zero = 1; }
        else zero = 0;
        __syncthreads();
    }
    o_r3[tid] = (rp == 0.f) ? 256.f : rp;
}

// ---------------- k_scalars ----------------
__global__ __launch_bounds__(1024) void k_scalars(const float* __restrict__ image,
        const float* __restrict__ r1pre, const float* __restrict__ o_r1,
        const float* __restrict__ o_r2,
        float* __restrict__ zeta, float* __restrict__ rho,
        float* __restrict__ imgt, float* __restrict__ eiP, float* __restrict__ eiM,
        float* __restrict__ Pv, float* __restrict__ Qv,
        float* __restrict__ E2P, float* __restrict__ E2M,
        float* __restrict__ o_err, float* __restrict__ o_es){
    int tid = threadIdx.x;
    for (int h = tid; h < Hn; h += 1024){
        float r1f = o_r1[h];
        float mask = (r1pre[h] != 0.f) ? 1.f : 0.f;
        float z = __fmul_rn(__fmul_rn(__fsub_rn(256.f, r1f), mask), 0.00390625f);
        zeta[h] = z;
        Pv[h] = __expf(r1f * 0.05f) * z;
        Qv[h] = __expf(-r1f * 0.05f) * z;
    }
    float acc = 0.f;
    for (int n = tid; n < Nn; n += 1024){
        float img = __fmul_rn(256.f, image[n]);
        float r2f = o_r2[n];
        float e = __fmul_rn(__fsub_rn(img, __fsub_rn(r2f, 4.0f)), 0.00390625f);
        o_err[n] = e;
        rho[n] = __fadd_rn(__fmul_rn(__fsub_rn(__fsub_rn(r2f, 4.0f), img), 0.00390625f), 0.15f);
        imgt[n] = img;
        eiP[n] = __expf(img * 0.05f);
        eiM[n] = __expf(-img * 0.05f);
        E2P[n] = __expf(r2f * 0.05f);
        E2M[n] = __expf(-r2f * 0.05f);
        acc = __fadd_rn(acc, __fmul_rn(e, e));
    }
    __shared__ float red[16];
    for (int off = 32; off >= 1; off >>= 1) acc += __shfl_down(acc, off);
    int lane = tid & 63, w = tid >> 6;
    if (lane == 0) red[w] = acc;
    __syncthreads();
    if (tid == 0){
        float s = 0.f;
        for (int q = 0; q < 16; ++q) s += red[q];
        *o_es = s;
    }
}

// ---------------- k_w1fix ----------------
__global__ __launch_bounds__(256) void k_w1fix(const float* __restrict__ W1,
        const float* __restrict__ imgt, const float* __restrict__ eiP,
        const float* __restrict__ eiM, const float* __restrict__ o_r1,
        const int* __restrict__ mh, const int* __restrict__ nRout,
        float* __restrict__ o_W1){
    int slot = blockIdx.x;
    if (slot >= *nRout) return;
    int h = mh[slot];
    int tid = threadIdx.x;
    float r1f = o_r1[h];
    float a = 0.01f * __expf(-r1f * 0.05f);
    float b = 0.01f * __expf( r1f * 0.05f);
    const float4* src = (const float4*)(W1 + (size_t)h * Nn);
    float4* dst = (float4*)(o_W1 + (size_t)h * Nn);
    const float4* ig = (const float4*)imgt;
    const float4* p4 = (const float4*)eiP;
    const float4* m4 = (const float4*)eiM;
    for (int i = tid; i < Nn / 4; i += 256){
        float4 s = src[i];
        float4 im = ig[i], pp = p4[i], mm = m4[i];
        s.x += (r1f >= im.x) ? a * pp.x : -(b * mm.x);
        s.y += (r1f >= im.y) ? a * pp.y : -(b * mm.y);
        s.z += (r1f >= im.z) ? a * pp.z : -(b * mm.z);
        s.w += (r1f >= im.w) ? a * pp.w : -(b * mm.w);
        dst[i] = s;
    }
}

// ---------------- k_w2fix ----------------
__global__ __launch_bounds__(128) void k_w2fix(
        const float* __restrict__ o_r1, const float* __restrict__ Pv,
        const float* __restrict__ Qv, const float* __restrict__ o_r2,
        const float* __restrict__ rho, const int* __restrict__ mh,
        const int* __restrict__ nRout, float* __restrict__ o_W2){
    __shared__ int   s_h[Tt];
    __shared__ float s_rv[Tt], s_pp[Tt], s_qq[Tt];
    int n = blockIdx.x, tid = threadIdx.x;
    int nRv = *nRout;
    for (int s = tid; s < nRv; s += 128){
        int h = mh[s];
        s_h[s] = h; s_rv[s] = o_r1[h]; s_pp[s] = Pv[h]; s_qq[s] = Qv[h];
    }
    __syncthreads();
    float r2f = o_r2[n], rh = rho[n];
    float A = 0.01f * rh * __expf(-r2f * 0.05f);
    float B = 0.01f * rh * __expf( r2f * 0.05f);
    for (int s = tid; s < nRv; s += 128){
        size_t idx = (size_t)n * Hn + s_h[s];
        float w = o_W2[idx];
        float rv = s_rv[s];
        w = clamp01(w + ((r2f >= rv) ? A * s_pp[s] : -(B * s_qq[s])));
        o_W2[idx] = w;
    }
}

// ---------------- k_w3new ----------------
__global__ __launch_bounds__(256) void k_w3new(const float* __restrict__ W3,
        const float* __restrict__ o_r2, const float* __restrict__ E2P,
        const float* __restrict__ E2M, const float* __restrict__ o_r3,
        float* __restrict__ o_W3){
    int c = blockIdx.x, tid = threadIdx.x;
    float r3f = o_r3[c];
    float a = 0.01f * __expf(-r3f * 0.05f);
    float b = 0.01f * __expf( r3f * 0.05f);
    const float4* src = (const float4*)(W3 + (size_t)c * Nn);
    float4* dst = (float4*)(o_W3 + (size_t)c * Nn);
    const float4* r24 = (const float4*)o_r2;
    const float4* p4 = (const float4*)E2P;
    const float4* m4 = (const float4*)E2M;
    for (int i = tid; i < Nn / 4; i += 256){
        float4 s = src[i]; float4 rv = r24[i]; float4 pp = p4[i]; float4 mm = m4[i];
        s.x += (r3f >= rv.x) ? a * pp.x : -(b * mm.x);
        s.y += (r3f >= rv.y) ? a * pp.y : -(b * mm.y);
        s.z += (r3f >= rv.z) ? a * pp.z : -(b * mm.z);
        s.w += (r3f >= rv.w) ? a * pp.w : -(b * mm.w);
        dst[i] = s;
    }
}

extern "C" void kernel_launch(void* const* d_in, const int* in_sizes, int n_in,
                              void* d_out, int out_size, void* d_ws, size_t ws_size,
                              hipStream_t stream){
    const float* image = (const float*)d_in[0];
    const float* W1   = (const float*)d_in[1];
    const float* W2   = (const float*)d_in[2];
    const float* W3   = (const float*)d_in[3];
    const float* thr1 = (const float*)d_in[4];
    const float* thr2 = (const float*)d_in[5];
    const float* thr3 = (const float*)d_in[6];

    float* out  = (float*)d_out;
    float* o_err = out;
    float* o_es  = out + 4096;
    float* o_r1  = out + 4097;
    float* o_r2  = out + 12289;
    float* o_r3  = out + 16385;
    float* o_W1  = out + 16513;
    float* o_W2  = o_W1 + (size_t)Hn * Nn;
    float* o_W3  = o_W2 + (size_t)Nn * Hn;

    float* ws = (float*)d_ws;
    float* G_T   = ws;                                  // H*T
    float* M     = G_T + (size_t)Hn * Tt;               // T*H
    float* W3T   = M + (size_t)Tt * Hn;                 // N*C
    float* colv  = W3T + (size_t)Nn * Cn;               // 256*N
    float4* cand = (float4*)(colv + (size_t)256 * Nn);  // T*CAP float4
    ull* spkb    = (ull*)(cand + (size_t)Tt * CAP);     // T*64
    float* r1pre = (float*)(spkb + (size_t)Tt * 64);    // H
    float* zeta  = r1pre + Hn;                          // H
    float* rho   = zeta + Hn;                           // N
    float* imgt  = rho + Nn;                            // N
    float* eiP   = imgt + Nn;                           // N
    float* eiM   = eiP + Nn;                            // N
    float* Pv    = eiM + Nn;                            // H
    float* Qv    = Pv + Hn;                             // H
    float* E2P   = Qv + Hn;                             // N
    float* E2M   = E2P + Nn;                            // N
    int* boff   = (int*)(E2M + Nn);                     // T+1
    int* sidx   = boff + (Tt + 1);                      // N
    int* j1s    = sidx + Nn;                            // T (h-indices)
    int* j1slot = j1s + Tt;                             // T
    int* mh     = j1slot + Tt;                          // 256
    int* nRout  = mh + 256;                             // 1
    unsigned* anyv = (unsigned*)(nRout + 1);            // T

    k_prep<<<1, 1024, 0, stream>>>(image, boff, sidx, anyv);
    k_gbuckets<<<Hn / 2, 256, 0, stream>>>(W1, boff, sidx, G_T);
    k_c1M<<<Hn / 32, 256, 0, stream>>>(G_T, M, r1pre, o_r1);
    k_sel<<<Tt, 256, 0, stream>>>(M, cand);
    k_w3t<<<128, 256, 0, stream>>>(W3, W3T);
    k_fused<<<1 + NB_W1 + NB_W2, 512, 0, stream>>>(
        M, cand, thr1, W1, W2, o_W1, o_W2, r1pre, o_r1, j1s);
    k_postmap<<<1, 256, 0, stream>>>(j1s, j1slot, mh, nRout);
    k_colg<<<256, 256, 0, stream>>>(W2, mh, nRout, colv);
    k_lif2<<<Nn / 64, 64, 0, stream>>>(colv, j1slot, thr2, o_r2, spkb, anyv);
    k_sim3<<<1, 128, 0, stream>>>(spkb, anyv, W3T, thr3, o_r3);
    k_scalars<<<1, 1024, 0, stream>>>(image, r1pre, o_r1, o_r2, zeta, rho,
                                      imgt, eiP, eiM, Pv, Qv, E2P, E2M, o_err, o_es);
    k_w1fix<<<256, 256, 0, stream>>>(W1, imgt, eiP, eiM, o_r1, mh, nRout, o_W1);
    k_w2fix<<<Nn, 128, 0, stream>>>(o_r1, Pv, Qv, o_r2, rho, mh, nRout, o_W2);
    k_w3new<<<Cn, 256, 0, stream>>>(W3, o_r2, E2P, E2M, o_r3, o_W3);
}